// Round 11
// baseline (2829.395 us; speedup 1.0000x reference)
//
#include <hip/hip_runtime.h>
#include <hip/hip_bf16.h>
#include <cstdio>
#include <cstddef>

#define B_    16
#define FIN_  128
#define N_    2048
#define K_    10
#define EPS_  1e-5f
#define SLOPE_ 0.01f

typedef float f32x4 __attribute__((ext_vector_type(4)));
typedef short s16x8 __attribute__((ext_vector_type(8)));
typedef short s16x4 __attribute__((ext_vector_type(4)));

// ---- stats region layout (floats) ----
constexpr int SUM_F=0,   SS_F=16,   SUM_X=32,  SS_X=48;
constexpr int SUM_A1=64, SS_A1=128, SUM_A2=192,SS_A2=448;
constexpr int SUM_I=704, SS_I=1216, SUM_O=1728,SS_O=1984;
constexpr int SCALE_F=2240, SHIFT_F=2256, SCALE_X=2272, SHIFT_X=2288;
constexpr int SCALE_A1=2304, SHIFT_A1=2368, SCALE_A2=2432, SHIFT_A2=2688;
constexpr int SCALE_I=2944, SHIFT_I=3456, SCALE_O=3968, SHIFT_O=4224;
constexpr int STATS_TOTAL=4480;
// aux region (in sq tail): S2[64] + G2[64*64]
constexpr int AUX_TOTAL = 64 + 4096;

// W2 GEMM refolded K: [0,2560) inte, [2560,3840) band (w=(k-2560)>>7, c=k&127), [3840,3968) self
constexpr int KW2_ = 3968;
// gemmI px chunking (Bd scratch = CHUNK*1408*2 B = 23 MB)
constexpr int CHUNK_ = 8192;

__device__ __forceinline__ float lrelu(float v){ return v >= 0.f ? v : SLOPE_*v; }
__device__ __forceinline__ float wave_sum(float v){
  #pragma unroll
  for (int o = 32; o > 0; o >>= 1) v += __shfl_down(v, o, 64);
  return v;
}
__device__ __forceinline__ unsigned short f2bf(float f){
  __hip_bfloat16 h = __float2bfloat16(f);
  return *reinterpret_cast<unsigned short*>(&h);
}
__device__ __forceinline__ float bf2f(unsigned short u){
  __hip_bfloat16 h = *reinterpret_cast<__hip_bfloat16*>(&u);
  return __bfloat162float(h);
}

// ---------------- zero stats + aux ----------------
__global__ void k_zero(float* s, float* aux){
  for (int i = threadIdx.x; i < STATS_TOTAL; i += 256) s[i] = 0.f;
  for (int i = threadIdx.x; i < AUX_TOTAL; i += 256) aux[i] = 0.f;
}

// ---------------- transpose x -> xT [b][n][c] ----------------
__global__ __launch_bounds__(256) void k_xt(const float* __restrict__ x, float* __restrict__ xT){
  __shared__ float t[32][33];
  const int b = blockIdx.z;
  const int c0 = blockIdx.x*32, n0 = blockIdx.y*32;
  const int tx = threadIdx.x & 31, ty = threadIdx.x >> 5;
  #pragma unroll
  for (int s = 0; s < 32; s += 8)
    t[ty+s][tx] = x[((size_t)b*FIN_ + c0+ty+s)*N_ + n0 + tx];
  __syncthreads();
  #pragma unroll
  for (int s = 0; s < 32; s += 8)
    xT[((size_t)b*N_ + n0+ty+s)*FIN_ + c0 + tx] = t[tx][ty+s];
}

// ---------------- sq norms: XLA:CPU AVX-512 minor-dim reduce (MATCHED — do not change) ----------------
__global__ __launch_bounds__(256) void k_sq(const float* __restrict__ x, float* __restrict__ sq){
  int id = blockIdx.x*256 + threadIdx.x;      // < B_*N_
  int b = id >> 11, n = id & (N_-1);
  const float* xb = x + (size_t)b*FIN_*N_ + n;
  float part[16];
  #pragma unroll
  for (int p = 0; p < 16; ++p){
    float a = 0.f;
    #pragma unroll
    for (int q = 0; q < 8; ++q){
      float v = xb[(size_t)(p + 16*q)*N_];
      a = __fmaf_rn(v, v, a);
    }
    part[p] = a;
  }
  #pragma unroll
  for (int off = 8; off > 0; off >>= 1){
    #pragma unroll
    for (int l = 0; l < off; ++l)
      part[l] = __fadd_rn(part[l], part[l+off]);
  }
  sq[id] = part[0];
}

// ---------------- kNN: top-10 (excluding self) ----------------
// ROUND-6 VERIFIED VERSION (475us, VGPR 100, VALU 67%) — do not restructure.
__global__ __launch_bounds__(256, 2) void k_knn(const float* __restrict__ x, const float* __restrict__ sq,
                                                int* __restrict__ idx){
  __shared__ __align__(16) char smem[61440];
  float* xi = (float*)smem;   // [128][64] (32 KB), later reused as merge buffers
  const int b = blockIdx.y, i0 = blockIdx.x*64;
  const float* xb = x + (size_t)b*FIN_*N_;
  for (int t = threadIdx.x; t < FIN_*64; t += 256){
    int c = t >> 6, ii = t & 63;
    xi[t] = xb[(size_t)c*N_ + i0 + ii];
  }
  __syncthreads();
  const int ty = threadIdx.x >> 4;      // 0..15: i group (4 i's)
  const int tx = threadIdx.x & 15;      // 0..15: j group (4 j's per step)
  const int ibase = ty*4;
  const f32x4 sqi = *(const f32x4*)&sq[b*N_ + i0 + ibase];
  float bd[4][10]; int bi[4][10];
  #pragma unroll
  for (int ii=0;ii<4;++ii)
    #pragma unroll
    for (int s=0;s<10;++s){ bd[ii][s] = 1e30f; bi[ii][s] = -1; }

  for (int j0 = 0; j0 < N_; j0 += 64){
    const int jb = j0 + tx*4;
    const float* xjp = xb + jb;
    f32x4 acc[4] = {};    // acc[ii][m]
    #pragma unroll 8
    for (int c = 0; c < FIN_; ++c){
      const f32x4 a  = *(const f32x4*)&xi[c*64 + ibase];
      const f32x4 bb = *(const f32x4*)&xjp[(size_t)c*N_];
      #pragma unroll
      for (int ii=0;ii<4;++ii){
        #pragma unroll
        for (int m=0;m<4;++m)
          acc[ii][m] = __fmaf_rn(a[ii], bb[m], acc[ii][m]);
      }
    }
    const f32x4 sqj = *(const f32x4*)&sq[b*N_ + jb];
    #pragma unroll
    for (int ii=0;ii<4;++ii){
      const int i = i0 + ibase + ii;
      #pragma unroll
      for (int m=0;m<4;++m){
        int j = jb + m;
        float d = __fadd_rn(__fadd_rn(__fmul_rn(-2.f, acc[ii][m]), sqi[ii]), sqj[m]);
        if (j == i) d = 1e30f;
        if (d < bd[ii][9]){
          bd[ii][9] = d; bi[ii][9] = j;
          #pragma unroll
          for (int s = 9; s > 0; --s){
            if (bd[ii][s] < bd[ii][s-1]){
              float td = bd[ii][s]; bd[ii][s] = bd[ii][s-1]; bd[ii][s-1] = td;
              int ti = bi[ii][s]; bi[ii][s] = bi[ii][s-1]; bi[ii][s-1] = ti;
            }
          }
        }
      }
    }
  }

  __syncthreads();   // xi dead; reuse smem for merge buffers
  float* dbuf = (float*)smem;                               // [(list*10+s)*64 + ilocal] (40 KB)
  unsigned short* ibuf = (unsigned short*)(smem + 40960);   // same index (20 KB)
  #pragma unroll
  for (int ii=0;ii<4;++ii)
    #pragma unroll
    for (int s=0;s<10;++s){
      dbuf[(tx*10+s)*64 + ibase+ii] = bd[ii][s];
      ibuf[(tx*10+s)*64 + ibase+ii] = (unsigned short)bi[ii][s];
    }
  __syncthreads();
  if (threadIdx.x < 64){
    const int rr = threadIdx.x;
    int p[16];
    #pragma unroll
    for (int qq=0;qq<16;++qq) p[qq]=0;
    int* op = idx + ((size_t)b*N_ + i0 + rr)*K_;
    for (int s = 0; s < K_; ++s){
      float dm = 1e38f; int im = 0x7fffffff; int qm = 0;
      #pragma unroll
      for (int qq = 0; qq < 16; ++qq){
        int pq = p[qq];
        float d  = (pq < 10) ? dbuf[(qq*10+pq)*64 + rr] : 1e38f;
        int   jd = (pq < 10) ? (int)ibuf[(qq*10+pq)*64 + rr] : 0x7fffffff;
        bool take = (d < dm) || (d == dm && jd < im);
        if (take){ dm = d; im = jd; qm = qq; }
      }
      #pragma unroll
      for (int qq = 0; qq < 16; ++qq) if (qm == qq) p[qq]++;
      op[s] = im;
    }
  }
}

// ---------------- conv_f / conv_x stats (xT layout; also spills y/vx to ytmp) ----------------
// 4 threads per px (kk strided by wave id): grid 512 blocks (was 128 — half the GPU was idle).
// Per-(px,kk) compute chains unchanged -> ytmp bit-identical; stats order already nondeterministic.
__global__ __launch_bounds__(256) void k_fx_stats(const float* __restrict__ xT, const float* __restrict__ pc,
                                                  const int* __restrict__ idx,
                                                  const float* __restrict__ Wf, const float* __restrict__ Wx,
                                                  float* __restrict__ stats, float* __restrict__ ytmp){
  __shared__ float wfT[256*16];
  __shared__ float wxT[6*16];
  for (int t = threadIdx.x; t < 256*16; t += 256){ int c = t >> 4, o = t & 15; wfT[t] = Wf[o*256 + c]; }
  if (threadIdx.x < 96){ int cc = threadIdx.x >> 4, o = threadIdx.x & 15; wxT[cc*16+o] = Wx[o*6+cc]; }
  __syncthreads();
  const int half = threadIdx.x >> 6;               // wave id: kk subset
  const int id = blockIdx.x*64 + (threadIdx.x & 63);
  const int b = id >> 11, n = id & (N_-1);
  const float* xs = xT + (size_t)id*FIN_;
  const float* pb = pc + (size_t)b*3*N_;
  float yc[16];
  #pragma unroll
  for (int o=0;o<16;++o) yc[o]=0.f;
  for (int c=0;c<FIN_;c+=4){
    const f32x4 v4 = *(const f32x4*)&xs[c];
    #pragma unroll
    for (int e=0;e<4;++e){
      float v = v4[e];
      #pragma unroll
      for (int o=0;o<16;++o) yc[o] += wfT[(c+e)*16+o]*v;
    }
  }
  float p0=pb[n], p1=pb[N_+n], p2=pb[2*N_+n];
  float sf[16], ssf[16], sx[16], ssx[16];
  #pragma unroll
  for (int o=0;o<16;++o){ sf[o]=0.f;ssf[o]=0.f;sx[o]=0.f;ssx[o]=0.f; }
  for (int kk=half; kk<K_; kk+=4){
    int j = idx[(size_t)id*K_ + kk];
    const float* xj = xT + ((size_t)b*N_ + j)*FIN_;
    float y[16];
    #pragma unroll
    for (int o=0;o<16;++o) y[o]=yc[o];
    for (int c=0;c<FIN_;c+=4){
      const f32x4 a4 = *(const f32x4*)&xj[c];
      const f32x4 s4 = *(const f32x4*)&xs[c];
      #pragma unroll
      for (int e=0;e<4;++e){
        float d = a4[e]-s4[e];
        #pragma unroll
        for (int o=0;o<16;++o) y[o] += wfT[(128+c+e)*16+o]*d;
      }
    }
    float q0=pb[j]-p0, q1=pb[N_+j]-p1, q2=pb[2*N_+j]-p2;
    float vx[16];
    #pragma unroll
    for (int o=0;o<16;++o){
      vx[o] = wxT[0*16+o]*p0 + wxT[1*16+o]*p1 + wxT[2*16+o]*p2
            + wxT[3*16+o]*q0 + wxT[4*16+o]*q1 + wxT[5*16+o]*q2;
    }
    #pragma unroll
    for (int o=0;o<16;++o){
      sf[o]+=y[o]; ssf[o]+=y[o]*y[o];
      sx[o]+=vx[o]; ssx[o]+=vx[o]*vx[o];
    }
    float* yt = ytmp + ((size_t)id*K_ + kk)*32;
    #pragma unroll
    for (int o=0;o<16;++o){ yt[o] = y[o]; yt[16+o] = vx[o]; }
  }
  #pragma unroll
  for (int o=0;o<16;++o){
    float v;
    v = wave_sum(sf[o]);  if ((threadIdx.x&63)==0) atomicAdd(&stats[SUM_F+o], v);
    v = wave_sum(ssf[o]); if ((threadIdx.x&63)==0) atomicAdd(&stats[SS_F+o], v);
    v = wave_sum(sx[o]);  if ((threadIdx.x&63)==0) atomicAdd(&stats[SUM_X+o], v);
    v = wave_sum(ssx[o]); if ((threadIdx.x&63)==0) atomicAdd(&stats[SS_X+o], v);
  }
}

// ---------------- finalize BN: scale/shift from sums ----------------
__global__ void k_finalize(float* stats, int sumoff, int ssoff, int nch, float cnt_inv,
                           const float* __restrict__ g, const float* __restrict__ bt,
                           int scoff, int shoff){
  int c = threadIdx.x;
  if (c < nch){
    float mean = stats[sumoff+c]*cnt_inv;
    float var  = stats[ssoff+c]*cnt_inv - mean*mean;
    float rstd = rsqrtf(var + EPS_);
    float sc = g[c]*rstd;
    stats[scoff+c] = sc;
    stats[shoff+c] = bt[c] - mean*sc;
  }
}

// ---------------- wprod apply: wp = lrelu(bn_f(y))*lrelu(bn_x(vx)) from ytmp ----------------
__global__ __launch_bounds__(256) void k_wapply(const float* __restrict__ ytmp, const float* __restrict__ stats,
                                                float* __restrict__ wprod){
  __shared__ float s4[64];   // scf[16] shf[16] scx[16] shx[16] (stats 2240..2304 contiguous)
  if (threadIdx.x < 64) s4[threadIdx.x] = stats[SCALE_F + threadIdx.x];
  __syncthreads();
  const int e = blockIdx.x*256 + threadIdx.x;   // < 327680
  const float* yt = ytmp + (size_t)e*32;
  float* wp = wprod + (size_t)e*16;
  #pragma unroll
  for (int o=0;o<16;++o){
    float a  = lrelu(yt[o]*s4[o] + s4[16+o]);
    float bb = lrelu(yt[16+o]*s4[32+o] + s4[48+o]);
    wp[o] = a*bb;
  }
}

// ---------------- a1 stats (conv 16->64 over wprod) ----------------
__global__ __launch_bounds__(256) void k_a1_stats(const float* __restrict__ wprod, const float* __restrict__ Wa1,
                                                  float* __restrict__ stats){
  __shared__ float wp[64*16];
  const int oc = threadIdx.x & 63, sub = threadIdx.x >> 6;
  float wa[16];
  #pragma unroll
  for (int j = 0; j < 16; ++j) wa[j] = Wa1[oc*16+j];
  float s = 0.f, ss = 0.f;
  for (int tile = blockIdx.x; tile < 5120; tile += gridDim.x){
    __syncthreads();
    for (int t = threadIdx.x; t < 1024; t += 256) wp[t] = wprod[(size_t)tile*1024 + t];
    __syncthreads();
    for (int p = sub*16; p < sub*16+16; ++p){
      float y = 0.f;
      #pragma unroll
      for (int j = 0; j < 16; ++j) y += wa[j]*wp[p*16+j];
      s += y; ss += y*y;
    }
  }
  atomicAdd(&stats[SUM_A1+oc], s);
  atomicAdd(&stats[SS_A1+oc], ss);
}

// ---------------- a2 Gram accumulate: S2 = Σ a1, G2 = Σ a1 a1^T over all (px,kk) ----------------
// Replaces a2_stats main loop: SS_A2[oc] = w^T G w (algebraically identical, ~4x less work).
__global__ __launch_bounds__(256) void k_a2g(const float* __restrict__ wprod, const float* __restrict__ Wa1,
                                             const float* __restrict__ stats, float* __restrict__ aux){
  __shared__ float wp[64*16];
  __shared__ float a1t[64*64];
  __shared__ float wa1T[16*64];
  __shared__ float sc1[64], sh1[64];
  for (int t=threadIdx.x;t<1024;t+=256){ int j=t&63, jj=t>>6; wa1T[jj*64+j] = Wa1[j*16+jj]; }
  if (threadIdx.x < 64){ sc1[threadIdx.x]=stats[SCALE_A1+threadIdx.x]; sh1[threadIdx.x]=stats[SHIFT_A1+threadIdx.x]; }
  const int i  = threadIdx.x >> 2;   // 0..63: Gram row
  const int jq = threadIdx.x & 3;    // 0..3: 16-col quad
  f32x4 g0={0.f,0.f,0.f,0.f}, g1={0.f,0.f,0.f,0.f}, g2={0.f,0.f,0.f,0.f}, g3={0.f,0.f,0.f,0.f};
  float s = 0.f;
  for (int tile = blockIdx.x; tile < 5120; tile += gridDim.x){
    __syncthreads();
    for (int t=threadIdx.x;t<1024;t+=256) wp[t] = wprod[(size_t)tile*1024 + t];
    __syncthreads();
    for (int t=threadIdx.x;t<4096;t+=256){
      int p = t >> 6, j = t & 63;
      float yv=0.f;
      #pragma unroll
      for (int jj=0;jj<16;++jj) yv += wa1T[jj*64+j]*wp[p*16+jj];
      a1t[t] = lrelu(yv*sc1[j]+sh1[j]);
    }
    __syncthreads();
    #pragma unroll 4
    for (int p=0;p<64;++p){
      const float ai = a1t[p*64 + i];
      const f32x4* row = (const f32x4*)&a1t[p*64 + jq*16];
      g0 += ai*row[0]; g1 += ai*row[1]; g2 += ai*row[2]; g3 += ai*row[3];
      if (jq == 0) s += ai;
    }
  }
  float* G = aux + 64;
  const int base = i*64 + jq*16;
  #pragma unroll
  for (int r=0;r<4;++r){ atomicAdd(&G[base+r],    g0[r]); }
  #pragma unroll
  for (int r=0;r<4;++r){ atomicAdd(&G[base+4+r],  g1[r]); }
  #pragma unroll
  for (int r=0;r<4;++r){ atomicAdd(&G[base+8+r],  g2[r]); }
  #pragma unroll
  for (int r=0;r<4;++r){ atomicAdd(&G[base+12+r], g3[r]); }
  if (jq == 0) atomicAdd(&aux[i], s);
}

// ---------------- a2 finalize from Gram: SUM_A2 = w.S2, SS_A2 = w^T G2 w ----------------
__global__ void k_a2fin(const float* __restrict__ aux, const float* __restrict__ Wa2,
                        float* __restrict__ stats){
  __shared__ float G[4096];
  __shared__ float S[64];
  for (int t = threadIdx.x; t < 4096; t += 256) G[t] = aux[64 + t];
  if (threadIdx.x < 64) S[threadIdx.x] = aux[threadIdx.x];
  __syncthreads();
  const int oc = threadIdx.x;
  float w[64];
  #pragma unroll
  for (int j=0;j<64;++j) w[j] = Wa2[oc*64+j];
  float sum = 0.f;
  #pragma unroll
  for (int j=0;j<64;++j) sum += w[j]*S[j];
  float ss = 0.f;
  for (int i=0;i<64;++i){
    float gi = 0.f;
    #pragma unroll
    for (int j=0;j<64;++j) gi += w[j]*G[i*64+j];
    ss += w[i]*gi;
  }
  stats[SUM_A2+oc] = sum;
  stats[SS_A2+oc]  = ss;
}

// ---------------- prep Ai for conv_Wi t5-split GEMM ----------------
__global__ __launch_bounds__(256) void k_prepAi(const float* __restrict__ Wi, unsigned short* __restrict__ Ai){
  const int total = 512*896;
  for (int e = blockIdx.x*256 + threadIdx.x; e < total; e += gridDim.x*256){
    int o = e / 896, k = e - o*896;
    float v;
    if (k < 768){
      int u = k >> 7, c = k & 127;
      v = Wi[(size_t)o*1536 + (128+c)*6 + u];
    } else {
      const float* p = &Wi[(size_t)o*1536 + (size_t)(k-768)*6];
      v = p[0]+p[1]+p[2]+p[3]+p[4]+p[5];
    }
    Ai[e] = f2bf(v);
  }
}

// ---------------- prep A2 hi/lo for W2 refolded GEMM ----------------
__global__ __launch_bounds__(256) void k_prepA2(const float* __restrict__ W2,
                                                unsigned short* __restrict__ A2hi,
                                                unsigned short* __restrict__ A2lo){
  const int total = 256*KW2_;
  for (int e = blockIdx.x*256 + threadIdx.x; e < total; e += gridDim.x*256){
    int oc = e / KW2_, k = e - oc*KW2_;
    const float* wr = &W2[(size_t)oc*5120];
    float v;
    if (k < 2560){
      int o = k & 511, t5 = k >> 9;
      int cch = o >> 1, w = (o & 1)*5 + t5;
      v = wr[cch*20 + 10 + w];
    } else if (k < 3840){
      int kk = k - 2560; int w = kk >> 7, c = kk & 127;
      v = wr[(128+c)*20 + w];
    } else {
      int c = k - 3840;
      float s = 0.f;
      #pragma unroll
      for (int w = 0; w < 10; ++w) s += wr[c*20+w] - wr[(128+c)*20+w];
      v = s;
    }
    unsigned short hi = f2bf(v);
    float lo = v - bf2f(hi);
    A2hi[e] = hi;
    A2lo[e] = f2bf(lo);
  }
}

// ---------------- gather: Bd[pxl][slab*128+c] bf16, slabs 0..9 = diff(x_jw - x_self), 10 = self ----------------
__global__ __launch_bounds__(256) void k_gather(const float* __restrict__ xT, const int* __restrict__ idx,
                                                unsigned short* __restrict__ Bd, int pxbase){
  const int e = blockIdx.x*256 + threadIdx.x;   // < CHUNK_*16
  const int pxl = e >> 4, sub = e & 15;
  const int px = pxbase + pxl;
  const int c0 = sub*8;
  const float* xs = xT + (size_t)px*FIN_ + c0;
  const f32x4 s0 = *(const f32x4*)&xs[0];
  const f32x4 s1 = *(const f32x4*)&xs[4];
  unsigned short* bo = Bd + (size_t)pxl*1408;
  const size_t bb = (size_t)(px >> 11)*N_*FIN_;
  const int* ip = idx + (size_t)px*K_;
  #pragma unroll
  for (int w = 0; w < 10; ++w){
    int j = ip[w];
    const float* xj = xT + bb + (size_t)j*FIN_ + c0;
    const f32x4 a0 = *(const f32x4*)&xj[0];
    const f32x4 a1 = *(const f32x4*)&xj[4];
    unsigned short tw[8];
    tw[0]=f2bf(a0.x-s0.x); tw[1]=f2bf(a0.y-s0.y); tw[2]=f2bf(a0.z-s0.z); tw[3]=f2bf(a0.w-s0.w);
    tw[4]=f2bf(a1.x-s1.x); tw[5]=f2bf(a1.y-s1.y); tw[6]=f2bf(a1.z-s1.z); tw[7]=f2bf(a1.w-s1.w);
    *(s16x8*)&bo[w*128 + c0] = *(const s16x8*)tw;
  }
  unsigned short tw[8];
  tw[0]=f2bf(s0.x); tw[1]=f2bf(s0.y); tw[2]=f2bf(s0.z); tw[3]=f2bf(s0.w);
  tw[4]=f2bf(s1.x); tw[5]=f2bf(s1.y); tw[6]=f2bf(s1.z); tw[7]=f2bf(s1.w);
  *(s16x8*)&bo[1280 + c0] = *(const s16x8*)tw;
}

// ---------------- conv_Wi t5-split GEMM (bf16 MFMA), Bd-fed: per t5: C[512 x CHUNK] = Ai * B_t5 ----------------
__global__ __launch_bounds__(256) void k_gemmI(const unsigned short* __restrict__ Bd,
                                               const unsigned short* __restrict__ Ai,
                                               __hip_bfloat16* __restrict__ ybuf, float* __restrict__ stats,
                                               int pxbase){
  __shared__ __align__(16) unsigned short As[128*72];
  __shared__ __align__(16) unsigned short Bs[128*72];
  const int o0 = blockIdx.x * 128;     // 4 row tiles (o)
  const int c0 = blockIdx.y * 128;     // CHUNK_/128 col tiles (local px)
  const int t5 = blockIdx.z;           // 5
  const int rowA = threadIdx.x >> 1;
  const int kA   = (threadIdx.x & 1)*32;
  const unsigned short* arow = Ai + (size_t)(o0+rowA)*896 + kA;
  const int colJ = threadIdx.x >> 1;
  const int kB   = (threadIdx.x & 1)*32;
  const unsigned short* brow = Bd + (size_t)(c0 + colJ)*1408;
  const int wave = threadIdx.x >> 6, lane = threadIdx.x & 63;
  const int quad = lane >> 4, l16 = lane & 15;
  const int wm = wave & 1, wn = wave >> 1;

  f32x4 acc[4][4] = {};

  for (int k0 = 0; k0 < 896; k0 += 64){
    __syncthreads();
    {
      unsigned short* dst = &As[rowA*72 + kA];
      *(s16x8*)&dst[0]  = *(const s16x8*)&arow[k0+0];
      *(s16x8*)&dst[8]  = *(const s16x8*)&arow[k0+8];
      *(s16x8*)&dst[16] = *(const s16x8*)&arow[k0+16];
      *(s16x8*)&dst[24] = *(const s16x8*)&arow[k0+24];
    }
    {
      const int kk = k0 + kB;          // 32-aligned; band/self boundary (768) never splits a run
      const unsigned short* src = brow + ((kk < 768) ? ((t5 + (kk >> 7))*128 + (kk & 127))
                                                     : (1280 + (kk - 768)));
      unsigned short* dst = &Bs[colJ*72 + kB];
      *(s16x8*)&dst[0]  = *(const s16x8*)&src[0];
      *(s16x8*)&dst[8]  = *(const s16x8*)&src[8];
      *(s16x8*)&dst[16] = *(const s16x8*)&src[16];
      *(s16x8*)&dst[24] = *(const s16x8*)&src[24];
    }
    __syncthreads();
    #pragma unroll
    for (int ks = 0; ks < 2; ++ks){
      s16x8 af[4], bfr[4];
      #pragma unroll
      for (int mt = 0; mt < 4; ++mt)
        af[mt] = *(const s16x8*)&As[(wm*64 + mt*16 + l16)*72 + ks*32 + quad*8];
      #pragma unroll
      for (int nt = 0; nt < 4; ++nt)
        bfr[nt] = *(const s16x8*)&Bs[(wn*64 + nt*16 + l16)*72 + ks*32 + quad*8];
      #pragma unroll
      for (int mt = 0; mt < 4; ++mt)
        #pragma unroll
        for (int nt = 0; nt < 4; ++nt)
          acc[mt][nt] = __builtin_amdgcn_mfma_f32_16x16x32_bf16(af[mt], bfr[nt], acc[mt][nt], 0, 0, 0);
    }
  }

  __syncthreads();
  float* red = (float*)As;   // reuse (256 floats)
  red[threadIdx.x] = 0.f;
  __syncthreads();
  #pragma unroll
  for (int mt = 0; mt < 4; ++mt){
    const int rowLbase = wm*64 + mt*16 + quad*4;
    #pragma unroll
    for (int reg = 0; reg < 4; ++reg){
      float s = 0.f, ss = 0.f;
      #pragma unroll
      for (int nt = 0; nt < 4; ++nt){ float v = acc[mt][nt][reg]; s += v; ss += v*v; }
      atomicAdd(&red[(rowLbase+reg)*2+0], s);
      atomicAdd(&red[(rowLbase+reg)*2+1], ss);
    }
  }
  #pragma unroll
  for (int mt = 0; mt < 4; ++mt){
    #pragma unroll
    for (int nt = 0; nt < 4; ++nt){
      const int px = pxbase + c0 + wn*64 + nt*16 + l16;
      const int ob = wm*64 + mt*16 + quad*4;
      s16x4 w;
      #pragma unroll
      for (int reg = 0; reg < 4; ++reg) w[reg] = (short)f2bf(acc[mt][nt][reg]);
      *(s16x4*)&ybuf[(size_t)px*2560 + t5*512 + o0 + ob] = w;
    }
  }
  __syncthreads();
  if (threadIdx.x < 128){
    atomicAdd(&stats[SUM_I + o0 + threadIdx.x], red[threadIdx.x*2+0]);
    atomicAdd(&stats[SS_I + o0 + threadIdx.x], red[threadIdx.x*2+1]);
  }
}

// ---------------- w-chain + softmax + bn_i + interleave-multiply (in-place on ybuf, bf16) ----------------
// Persistent blocks: wa1T/sc/sh staged once, Wa2 row held in VGPRs (f32x4[16]); 16 px per block.
__global__ __launch_bounds__(256, 4) void k_wchain(const float* __restrict__ wprod, const float* __restrict__ Wa1,
                                                   const float* __restrict__ Wa2, const float* __restrict__ stats,
                                                   __hip_bfloat16* __restrict__ ybuf, int pxPerBlk){
  __shared__ float wp[160];
  __shared__ float a1l[640];
  __shared__ float wa1T[16*64];
  __shared__ float sc1[64], sh1[64];
  for (int t = threadIdx.x; t < 1024; t += 256){ int j = t & 63, jj = t >> 6; wa1T[jj*64+j] = Wa1[j*16+jj]; }
  if (threadIdx.x < 64){ sc1[threadIdx.x]=stats[SCALE_A1+threadIdx.x]; sh1[threadIdx.x]=stats[SHIFT_A1+threadIdx.x]; }
  const int c = threadIdx.x;
  f32x4 wa2v[16];
  #pragma unroll
  for (int j4=0;j4<16;++j4) wa2v[j4] = *(const f32x4*)&Wa2[c*64 + j4*4];
  const float sc2 = stats[SCALE_A2+c], sh2 = stats[SHIFT_A2+c];
  const float sci0 = stats[SCALE_I + 2*c], shi0 = stats[SHIFT_I + 2*c];
  const float sci1 = stats[SCALE_I + 2*c+1], shi1 = stats[SHIFT_I + 2*c+1];

  for (int pp = 0; pp < pxPerBlk; ++pp){
    const size_t px = (size_t)blockIdx.x*pxPerBlk + pp;
    __syncthreads();
    if (threadIdx.x < 160) wp[threadIdx.x] = wprod[px*160 + threadIdx.x];
    __syncthreads();
    for (int t = threadIdx.x; t < 640; t += 256){
      int kk = t >> 6, j = t & 63;
      float y=0.f;
      #pragma unroll
      for (int jj=0;jj<16;++jj) y += wa1T[jj*64+j]*wp[kk*16+jj];
      a1l[kk*64+j] = lrelu(y*sc1[j]+sh1[j]);
    }
    __syncthreads();
    float wt[10];
    #pragma unroll
    for (int kk=0;kk<10;++kk){
      f32x4 acc = {0.f,0.f,0.f,0.f};
      #pragma unroll
      for (int j4=0;j4<16;++j4){
        const f32x4 a = *(const f32x4*)&a1l[kk*64 + j4*4];
        acc += wa2v[j4]*a;
      }
      float y = (acc.x+acc.y)+(acc.z+acc.w);
      wt[kk] = lrelu(y*sc2+sh2);
    }
    float mx = wt[0];
    #pragma unroll
    for (int kk=1;kk<10;++kk) mx = fmaxf(mx, wt[kk]);
    float sum = 0.f;
    #pragma unroll
    for (int kk=0;kk<10;++kk){ wt[kk] = __expf(wt[kk]-mx); sum += wt[kk]; }
    float inv = 1.f/sum;
    __hip_bfloat16* yb = ybuf + px*2560;
    #pragma unroll
    for (int q = 0; q < 10; ++q){
      const int t5q = (q < 5) ? q : q-5;
      const int ii  = t5q*512 + 2*c + ((q < 5) ? 0 : 1);
      float v = __bfloat162float(yb[ii]);
      float sc = (q < 5) ? sci0 : sci1;
      float sh = (q < 5) ? shi0 : shi1;
      yb[ii] = __float2bfloat16(lrelu(v*sc+sh) * (wt[q]*inv));
    }
  }
}

// ---------------- W2 refolded GEMM (split-bf16 MFMA): outpre[256 x 32768]; fused o-stats ----------------
__global__ __launch_bounds__(256) void k_w2(const float* __restrict__ xT, const int* __restrict__ idx,
                                            const __hip_bfloat16* __restrict__ inte,
                                            const unsigned short* __restrict__ A2hi,
                                            const unsigned short* __restrict__ A2lo,
                                            float* __restrict__ outpre, float* __restrict__ stats){
  __shared__ __align__(16) unsigned short AsH[128*40];
  __shared__ __align__(16) unsigned short AsL[128*40];
  __shared__ __align__(16) unsigned short BsH[128*40];
  __shared__ __align__(16) unsigned short BsL[128*40];
  __shared__ int sIdx[128*10];
  const int r0 = blockIdx.x * 128;   // 2 row tiles (oc)
  const int c0 = blockIdx.y * 128;   // 256 col tiles (px)
  for (int t = threadIdx.x; t < 1280; t += 256) sIdx[t] = idx[(size_t)c0*10 + t];
  const int rowA  = threadIdx.x >> 1;
  const int halfA = threadIdx.x & 1;
  const unsigned short* ahrow = A2hi + (size_t)(r0+rowA)*KW2_ + halfA*16;
  const unsigned short* alrow = A2lo + (size_t)(r0+rowA)*KW2_ + halfA*16;
  const int colJ  = threadIdx.x >> 1;
  const int cHalf = (threadIdx.x & 1)*16;
  const int pxJ   = c0 + colJ;
  const size_t selfJ  = (size_t)pxJ*FIN_;
  const size_t bbaseJ = (size_t)(pxJ >> 11)*N_*FIN_;
  const __hip_bfloat16* ibJ = inte + (size_t)pxJ*2560;
  const int wave = threadIdx.x >> 6, lane = threadIdx.x & 63;
  const int quad = lane >> 4, l16 = lane & 15;
  const int wm = wave & 1, wn = wave >> 1;

  f32x4 acc[4][4] = {};

  for (int k0 = 0; k0 < KW2_; k0 += 32){
    __syncthreads();
    {
      *(s16x8*)&AsH[rowA*40 + halfA*16]     = *(const s16x8*)&ahrow[k0];
      *(s16x8*)&AsH[rowA*40 + halfA*16 + 8] = *(const s16x8*)&ahrow[k0+8];
      *(s16x8*)&AsL[rowA*40 + halfA*16]     = *(const s16x8*)&alrow[k0];
      *(s16x8*)&AsL[rowA*40 + halfA*16 + 8] = *(const s16x8*)&alrow[k0+8];
    }
    if (k0 < 2560){
      *(s16x8*)&BsH[colJ*40 + cHalf]     = *(const s16x8*)(ibJ + k0 + cHalf);
      *(s16x8*)&BsH[colJ*40 + cHalf + 8] = *(const s16x8*)(ibJ + k0 + cHalf + 8);
    } else {
      const float* src;
      if (k0 < 3840){
        const int w  = (k0 - 2560) >> 7;
        const int cb = ((k0 - 2560) & 127) + cHalf;
        const int j  = sIdx[colJ*10 + w];
        src = &xT[bbaseJ + (size_t)j*FIN_ + cb];
      } else {
        src = &xT[selfJ + (k0 - 3840) + cHalf];
      }
      unsigned short th[16], tl[16];
      #pragma unroll
      for (int q = 0; q < 4; ++q){
        const f32x4 v = *(const f32x4*)&src[q*4];
        #pragma unroll
        for (int e2 = 0; e2 < 4; ++e2){
          float f = v[e2];
          unsigned short h = f2bf(f);
          float r = f - bf2f(h);
          th[q*4+e2] = h;
          tl[q*4+e2] = f2bf(r);
        }
      }
      *(s16x8*)&BsH[colJ*40 + cHalf]     = *(const s16x8*)&th[0];
      *(s16x8*)&BsH[colJ*40 + cHalf + 8] = *(const s16x8*)&th[8];
      *(s16x8*)&BsL[colJ*40 + cHalf]     = *(const s16x8*)&tl[0];
      *(s16x8*)&BsL[colJ*40 + cHalf + 8] = *(const s16x8*)&tl[8];
    }
    __syncthreads();
    s16x8 ah[4], al[4], bh[4];
    #pragma unroll
    for (int mt = 0; mt < 4; ++mt){
      ah[mt] = *(const s16x8*)&AsH[(wm*64 + mt*16 + l16)*40 + quad*8];
      al[mt] = *(const s16x8*)&AsL[(wm*64 + mt*16 + l16)*40 + quad*8];
    }
    #pragma unroll
    for (int nt = 0; nt < 4; ++nt)
      bh[nt] = *(const s16x8*)&BsH[(wn*64 + nt*16 + l16)*40 + quad*8];
    #pragma unroll
    for (int mt = 0; mt < 4; ++mt)
      #pragma unroll
      for (int nt = 0; nt < 4; ++nt){
        acc[mt][nt] = __builtin_amdgcn_mfma_f32_16x16x32_bf16(ah[mt], bh[nt], acc[mt][nt], 0, 0, 0);
        acc[mt][nt] = __builtin_amdgcn_mfma_f32_16x16x32_bf16(al[mt], bh[nt], acc[mt][nt], 0, 0, 0);
      }
    if (k0 >= 2560){
      s16x8 bl[4];
      #pragma unroll
      for (int nt = 0; nt < 4; ++nt)
        bl[nt] = *(const s16x8*)&BsL[(wn*64 + nt*16 + l16)*40 + quad*8];
      #pragma unroll
      for (int mt = 0; mt < 4; ++mt)
        #pragma unroll
        for (int nt = 0; nt < 4; ++nt)
          acc[mt][nt] = __builtin_amdgcn_mfma_f32_16x16x32_bf16(ah[mt], bl[nt], acc[mt][nt], 0, 0, 0);
    }
  }

  __syncthreads();
  float* red = (float*)AsH;   // reuse (256 floats)
  red[threadIdx.x] = 0.f;
  __syncthreads();
  #pragma unroll
  for (int mt = 0; mt < 4; ++mt){
    const int rowLbase = wm*64 + mt*16 + quad*4;
    #pragma unroll
    for (int reg = 0; reg < 4; ++reg){
      float s = 0.f, ss = 0.f;
      #pragma unroll
      for (int nt = 0; nt < 4; ++nt){ float v = acc[mt][nt][reg]; s += v; ss += v*v; }
      atomicAdd(&red[(rowLbase+reg)*2+0], s);
      atomicAdd(&red[(rowLbase+reg)*2+1], ss);
    }
  }
  #pragma unroll
  for (int mt = 0; mt < 4; ++mt){
    #pragma unroll
    for (int nt = 0; nt < 4; ++nt){
      const int col = c0 + wn*64 + nt*16 + l16;
      const int rowb = r0 + wm*64 + mt*16 + quad*4;
      #pragma unroll
      for (int reg = 0; reg < 4; ++reg)
        outpre[(size_t)(rowb+reg)*32768 + col] = acc[mt][nt][reg];
    }
  }
  __syncthreads();
  if (threadIdx.x < 128){
    atomicAdd(&stats[SUM_O + r0 + threadIdx.x], red[threadIdx.x*2+0]);
    atomicAdd(&stats[SS_O + r0 + threadIdx.x], red[threadIdx.x*2+1]);
  }
}

// ---------------- final: bn2 + relu + reshape to [B,128,4096] ----------------
__global__ __launch_bounds__(256) void k_final(const float* __restrict__ outpre, const float* __restrict__ stats,
                                               float* __restrict__ out){
  const unsigned total = (unsigned)B_*128u*4096u;
  for (unsigned e = blockIdx.x*256u + threadIdx.x; e < total; e += gridDim.x*256u){
    unsigned b = e >> 19;
    unsigned rem = e & ((1u<<19)-1u);
    unsigned f = rem >> 12;
    unsigned m = rem & 4095u;
    unsigned half = m >> 11;
    unsigned n = m & 2047u;
    unsigned c = f*2u + half;
    float pre = outpre[(size_t)c*32768 + b*2048 + n];
    float v = pre*stats[SCALE_O+c] + stats[SHIFT_O+c];
    out[e] = fmaxf(v, 0.f);
  }
}

extern "C" void kernel_launch(void* const* d_in, const int* in_sizes, int n_in,
                              void* d_out, int out_size, void* d_ws, size_t ws_size,
                              hipStream_t stream) {
  (void)in_sizes; (void)n_in; (void)out_size;
  const float* x    = (const float*)d_in[0];
  const float* pc   = (const float*)d_in[1];
  const float* Wf   = (const float*)d_in[2];
  const float* gf   = (const float*)d_in[4];
  const float* btf  = (const float*)d_in[5];
  const float* Wx   = (const float*)d_in[6];
  const float* gx   = (const float*)d_in[8];
  const float* btx  = (const float*)d_in[9];
  const float* Wa1  = (const float*)d_in[10];
  const float* ga1  = (const float*)d_in[12];
  const float* bta1 = (const float*)d_in[13];
  const float* Wa2  = (const float*)d_in[14];
  const float* ga2  = (const float*)d_in[16];
  const float* bta2 = (const float*)d_in[17];
  const float* Wi   = (const float*)d_in[18];
  const float* gi   = (const float*)d_in[20];
  const float* bti  = (const float*)d_in[21];
  const float* W2   = (const float*)d_in[22];
  const float* g2   = (const float*)d_in[24];
  const float* bt2  = (const float*)d_in[25];
  float* out = (float*)d_out;

  char* ws = (char*)d_ws;
  float*  stats  = (float*)ws;                          //        0 ..    32768
  int*    idx    = (int*)  (ws + 32768);                //    32768 ..  1343488
  float*  sq     = (float*)(ws + 1343488);              //  1343488 ..  1605632 (uses first 131072)
  float*  aux    = (float*)(ws + 1474560);              //  S2[64]+G2[4096] in sq tail (dead after knn)
  float*  wprod  = (float*)(ws + 1605632);              //  1605632 .. 22577152
  float*  xT     = (float*)(ws + 22577152);             // 22577152 .. 39354368
  // A2hi/A2lo bf16 [256 x 3968] = 2,031,616 B each -> 39354368 .. 43417600
  unsigned short* A2hi = (unsigned short*)(ws + 39354368);
  unsigned short* A2lo = (unsigned short*)(ws + 41385984);
  float*  outpre = (float*)(ws + 44597248);             // 44597248 .. 78151680
  // Ai (bf16 [512x896] = 917,504 B) at 44597248..45514752; Bd chunk (bf16 [8192x1408] = 23,068,672 B)
  // at 45645824..68714496 — both inside outpre region, consumed before k_w2 writes outpre.
  unsigned short* Ai = (unsigned short*)(ws + 44597248);
  unsigned short* Bd = (unsigned short*)(ws + 45645824);
  __hip_bfloat16* ybuf = (__hip_bfloat16*)(ws + 78151680); // 78151680 .. 245923840
  // ytmp (fp32 [327680 x 32] = 41,943,040 B) overlaps ybuf: consumed by k_wapply before k_gemmI writes ybuf.
  float* ytmp = (float*)(ws + 78151680);
  if (ws_size < 245923840ULL) {
    fprintf(stderr, "kernel_launch: ws_size %zu < required 245923840\n", ws_size);
    return;
  }

  k_zero<<<1, 256, 0, stream>>>(stats, aux);
  k_xt<<<dim3(FIN_/32, N_/32, B_), 256, 0, stream>>>(x, xT);
  k_sq<<<(B_*N_)/256, 256, 0, stream>>>(x, sq);
  k_knn<<<dim3(N_/64, B_), 256, 0, stream>>>(x, sq, idx);
  k_prepAi<<<1024, 256, 0, stream>>>(Wi, Ai);
  k_prepA2<<<1024, 256, 0, stream>>>(W2, A2hi, A2lo);

  k_fx_stats<<<(B_*N_)/64, 256, 0, stream>>>(xT, pc, idx, Wf, Wx, stats, ytmp);
  k_finalize<<<1, 512, 0, stream>>>(stats, SUM_F, SS_F, 16, 1.f/327680.f, gf, btf, SCALE_F, SHIFT_F);
  k_finalize<<<1, 512, 0, stream>>>(stats, SUM_X, SS_X, 16, 1.f/327680.f, gx, btx, SCALE_X, SHIFT_X);

  k_wapply<<<1280, 256, 0, stream>>>(ytmp, stats, wprod);
  k_a1_stats<<<512, 256, 0, stream>>>(wprod, Wa1, stats);
  k_finalize<<<1, 512, 0, stream>>>(stats, SUM_A1, SS_A1, 64, 1.f/327680.f, ga1, bta1, SCALE_A1, SHIFT_A1);

  k_a2g<<<512, 256, 0, stream>>>(wprod, Wa1, stats, aux);
  k_a2fin<<<1, 256, 0, stream>>>(aux, Wa2, stats);
  k_finalize<<<1, 512, 0, stream>>>(stats, SUM_A2, SS_A2, 256, 1.f/327680.f, ga2, bta2, SCALE_A2, SHIFT_A2);

  for (int ch = 0; ch < (B_*N_)/CHUNK_; ++ch){
    k_gather<<<(CHUNK_*16)/256, 256, 0, stream>>>(xT, idx, Bd, ch*CHUNK_);
    k_gemmI<<<dim3(4, CHUNK_/128, 5), 256, 0, stream>>>(Bd, Ai, ybuf, stats, ch*CHUNK_);
  }
  k_finalize<<<1, 512, 0, stream>>>(stats, SUM_I, SS_I, 512, 1.f/163840.f, gi, bti, SCALE_I, SHIFT_I);

  k_wchain<<<2048, 256, 0, stream>>>(wprod, Wa1, Wa2, stats, ybuf, (B_*N_)/2048);

  k_w2<<<dim3(2, 256), 256, 0, stream>>>(xT, idx, ybuf, A2hi, A2lo, outpre, stats);
  k_finalize<<<1, 512, 0, stream>>>(stats, SUM_O, SS_O, 256, 1.f/32768.f, g2, bt2, SCALE_O, SHIFT_O);

  k_final<<<4096, 256, 0, stream>>>(outpre, stats, out);
}

// Round 12
// 2443.416 us; speedup vs baseline: 1.1580x; 1.1580x over previous
//
#include <hip/hip_runtime.h>
#include <hip/hip_bf16.h>
#include <cstdio>
#include <cstddef>

#define B_    16
#define FIN_  128
#define N_    2048
#define K_    10
#define EPS_  1e-5f
#define SLOPE_ 0.01f

typedef float f32x4 __attribute__((ext_vector_type(4)));
typedef short s16x8 __attribute__((ext_vector_type(8)));
typedef short s16x4 __attribute__((ext_vector_type(4)));

// ---- stats region layout (floats) ----
constexpr int SUM_F=0,   SS_F=16,   SUM_X=32,  SS_X=48;
constexpr int SUM_A1=64, SS_A1=128, SUM_A2=192,SS_A2=448;
constexpr int SUM_I=704, SS_I=1216, SUM_O=1728,SS_O=1984;
constexpr int SCALE_F=2240, SHIFT_F=2256, SCALE_X=2272, SHIFT_X=2288;
constexpr int SCALE_A1=2304, SHIFT_A1=2368, SCALE_A2=2432, SHIFT_A2=2688;
constexpr int SCALE_I=2944, SHIFT_I=3456, SCALE_O=3968, SHIFT_O=4224;
constexpr int STATS_TOTAL=4480;
// aux region (in sq tail): S2[64] + G2[64*64]
constexpr int AUX_TOTAL = 64 + 4096;

// W2 GEMM refolded K: [0,2560) inte, [2560,3840) band (w=(k-2560)>>7, c=k&127), [3840,3968) self
constexpr int KW2_ = 3968;
// gemmI px chunking (Bd scratch = CHUNK*1408*2 B = 23 MB)
constexpr int CHUNK_ = 8192;

__device__ __forceinline__ float lrelu(float v){ return v >= 0.f ? v : SLOPE_*v; }
__device__ __forceinline__ float wave_sum(float v){
  #pragma unroll
  for (int o = 32; o > 0; o >>= 1) v += __shfl_down(v, o, 64);
  return v;
}
__device__ __forceinline__ unsigned short f2bf(float f){
  __hip_bfloat16 h = __float2bfloat16(f);
  return *reinterpret_cast<unsigned short*>(&h);
}
__device__ __forceinline__ float bf2f(unsigned short u){
  __hip_bfloat16 h = *reinterpret_cast<__hip_bfloat16*>(&u);
  return __bfloat162float(h);
}

// ---------------- zero stats + aux ----------------
__global__ void k_zero(float* s, float* aux){
  for (int i = threadIdx.x; i < STATS_TOTAL; i += 256) s[i] = 0.f;
  for (int i = threadIdx.x; i < AUX_TOTAL; i += 256) aux[i] = 0.f;
}

// ---------------- transpose x -> xT [b][n][c] ----------------
__global__ __launch_bounds__(256) void k_xt(const float* __restrict__ x, float* __restrict__ xT){
  __shared__ float t[32][33];
  const int b = blockIdx.z;
  const int c0 = blockIdx.x*32, n0 = blockIdx.y*32;
  const int tx = threadIdx.x & 31, ty = threadIdx.x >> 5;
  #pragma unroll
  for (int s = 0; s < 32; s += 8)
    t[ty+s][tx] = x[((size_t)b*FIN_ + c0+ty+s)*N_ + n0 + tx];
  __syncthreads();
  #pragma unroll
  for (int s = 0; s < 32; s += 8)
    xT[((size_t)b*N_ + n0+ty+s)*FIN_ + c0 + tx] = t[tx][ty+s];
}

// ---------------- sq norms: XLA:CPU AVX-512 minor-dim reduce (MATCHED — do not change) ----------------
__global__ __launch_bounds__(256) void k_sq(const float* __restrict__ x, float* __restrict__ sq){
  int id = blockIdx.x*256 + threadIdx.x;      // < B_*N_
  int b = id >> 11, n = id & (N_-1);
  const float* xb = x + (size_t)b*FIN_*N_ + n;
  float part[16];
  #pragma unroll
  for (int p = 0; p < 16; ++p){
    float a = 0.f;
    #pragma unroll
    for (int q = 0; q < 8; ++q){
      float v = xb[(size_t)(p + 16*q)*N_];
      a = __fmaf_rn(v, v, a);
    }
    part[p] = a;
  }
  #pragma unroll
  for (int off = 8; off > 0; off >>= 1){
    #pragma unroll
    for (int l = 0; l < off; ++l)
      part[l] = __fadd_rn(part[l], part[l+off]);
  }
  sq[id] = part[0];
}

// ---------------- kNN: top-10 (excluding self) ----------------
// ROUND-6 VERIFIED VERSION (475us, VGPR 100, VALU 67%) — do not restructure.
__global__ __launch_bounds__(256, 2) void k_knn(const float* __restrict__ x, const float* __restrict__ sq,
                                                int* __restrict__ idx){
  __shared__ __align__(16) char smem[61440];
  float* xi = (float*)smem;   // [128][64] (32 KB), later reused as merge buffers
  const int b = blockIdx.y, i0 = blockIdx.x*64;
  const float* xb = x + (size_t)b*FIN_*N_;
  for (int t = threadIdx.x; t < FIN_*64; t += 256){
    int c = t >> 6, ii = t & 63;
    xi[t] = xb[(size_t)c*N_ + i0 + ii];
  }
  __syncthreads();
  const int ty = threadIdx.x >> 4;      // 0..15: i group (4 i's)
  const int tx = threadIdx.x & 15;      // 0..15: j group (4 j's per step)
  const int ibase = ty*4;
  const f32x4 sqi = *(const f32x4*)&sq[b*N_ + i0 + ibase];
  float bd[4][10]; int bi[4][10];
  #pragma unroll
  for (int ii=0;ii<4;++ii)
    #pragma unroll
    for (int s=0;s<10;++s){ bd[ii][s] = 1e30f; bi[ii][s] = -1; }

  for (int j0 = 0; j0 < N_; j0 += 64){
    const int jb = j0 + tx*4;
    const float* xjp = xb + jb;
    f32x4 acc[4] = {};    // acc[ii][m]
    #pragma unroll 8
    for (int c = 0; c < FIN_; ++c){
      const f32x4 a  = *(const f32x4*)&xi[c*64 + ibase];
      const f32x4 bb = *(const f32x4*)&xjp[(size_t)c*N_];
      #pragma unroll
      for (int ii=0;ii<4;++ii){
        #pragma unroll
        for (int m=0;m<4;++m)
          acc[ii][m] = __fmaf_rn(a[ii], bb[m], acc[ii][m]);
      }
    }
    const f32x4 sqj = *(const f32x4*)&sq[b*N_ + jb];
    #pragma unroll
    for (int ii=0;ii<4;++ii){
      const int i = i0 + ibase + ii;
      #pragma unroll
      for (int m=0;m<4;++m){
        int j = jb + m;
        float d = __fadd_rn(__fadd_rn(__fmul_rn(-2.f, acc[ii][m]), sqi[ii]), sqj[m]);
        if (j == i) d = 1e30f;
        if (d < bd[ii][9]){
          bd[ii][9] = d; bi[ii][9] = j;
          #pragma unroll
          for (int s = 9; s > 0; --s){
            if (bd[ii][s] < bd[ii][s-1]){
              float td = bd[ii][s]; bd[ii][s] = bd[ii][s-1]; bd[ii][s-1] = td;
              int ti = bi[ii][s]; bi[ii][s] = bi[ii][s-1]; bi[ii][s-1] = ti;
            }
          }
        }
      }
    }
  }

  __syncthreads();   // xi dead; reuse smem for merge buffers
  float* dbuf = (float*)smem;                               // [(list*10+s)*64 + ilocal] (40 KB)
  unsigned short* ibuf = (unsigned short*)(smem + 40960);   // same index (20 KB)
  #pragma unroll
  for (int ii=0;ii<4;++ii)
    #pragma unroll
    for (int s=0;s<10;++s){
      dbuf[(tx*10+s)*64 + ibase+ii] = bd[ii][s];
      ibuf[(tx*10+s)*64 + ibase+ii] = (unsigned short)bi[ii][s];
    }
  __syncthreads();
  if (threadIdx.x < 64){
    const int rr = threadIdx.x;
    int p[16];
    #pragma unroll
    for (int qq=0;qq<16;++qq) p[qq]=0;
    int* op = idx + ((size_t)b*N_ + i0 + rr)*K_;
    for (int s = 0; s < K_; ++s){
      float dm = 1e38f; int im = 0x7fffffff; int qm = 0;
      #pragma unroll
      for (int qq = 0; qq < 16; ++qq){
        int pq = p[qq];
        float d  = (pq < 10) ? dbuf[(qq*10+pq)*64 + rr] : 1e38f;
        int   jd = (pq < 10) ? (int)ibuf[(qq*10+pq)*64 + rr] : 0x7fffffff;
        bool take = (d < dm) || (d == dm && jd < im);
        if (take){ dm = d; im = jd; qm = qq; }
      }
      #pragma unroll
      for (int qq = 0; qq < 16; ++qq) if (qm == qq) p[qq]++;
      op[s] = im;
    }
  }
}

// ---------------- conv_f / conv_x stats (xT layout; also spills y/vx to ytmp) ----------------
// ROUND-10 body (1 thread/px, unrolled kk chain — the ILP carries this kernel) + grid.y=2 kk-split
// (kk in [base, base+5), constant trip count 5 keeps the unroll). 256 blocks -> all CUs busy.
// R11's runtime-strided kk loop killed the unroll (VALUBusy 2.2%, 865us) — do not repeat.
__global__ __launch_bounds__(256) void k_fx_stats(const float* __restrict__ xT, const float* __restrict__ pc,
                                                  const int* __restrict__ idx,
                                                  const float* __restrict__ Wf, const float* __restrict__ Wx,
                                                  float* __restrict__ stats, float* __restrict__ ytmp){
  __shared__ float wfT[256*16];
  __shared__ float wxT[6*16];
  for (int t = threadIdx.x; t < 256*16; t += 256){ int c = t >> 4, o = t & 15; wfT[t] = Wf[o*256 + c]; }
  if (threadIdx.x < 96){ int cc = threadIdx.x >> 4, o = threadIdx.x & 15; wxT[cc*16+o] = Wx[o*6+cc]; }
  __syncthreads();
  const int id = blockIdx.x*256 + threadIdx.x;
  const int kbase = blockIdx.y*5;
  const int b = id >> 11, n = id & (N_-1);
  const float* xs = xT + (size_t)id*FIN_;
  const float* pb = pc + (size_t)b*3*N_;
  float yc[16];
  #pragma unroll
  for (int o=0;o<16;++o) yc[o]=0.f;
  for (int c=0;c<FIN_;c+=4){
    const f32x4 v4 = *(const f32x4*)&xs[c];
    #pragma unroll
    for (int e=0;e<4;++e){
      float v = v4[e];
      #pragma unroll
      for (int o=0;o<16;++o) yc[o] += wfT[(c+e)*16+o]*v;
    }
  }
  float p0=pb[n], p1=pb[N_+n], p2=pb[2*N_+n];
  float sf[16], ssf[16], sx[16], ssx[16];
  #pragma unroll
  for (int o=0;o<16;++o){ sf[o]=0.f;ssf[o]=0.f;sx[o]=0.f;ssx[o]=0.f; }
  #pragma unroll
  for (int t5 = 0; t5 < 5; ++t5){
    const int kk = kbase + t5;
    int j = idx[(size_t)id*K_ + kk];
    const float* xj = xT + ((size_t)b*N_ + j)*FIN_;
    float y[16];
    #pragma unroll
    for (int o=0;o<16;++o) y[o]=yc[o];
    for (int c=0;c<FIN_;c+=4){
      const f32x4 a4 = *(const f32x4*)&xj[c];
      const f32x4 s4 = *(const f32x4*)&xs[c];
      #pragma unroll
      for (int e=0;e<4;++e){
        float d = a4[e]-s4[e];
        #pragma unroll
        for (int o=0;o<16;++o) y[o] += wfT[(128+c+e)*16+o]*d;
      }
    }
    float q0=pb[j]-p0, q1=pb[N_+j]-p1, q2=pb[2*N_+j]-p2;
    float vx[16];
    #pragma unroll
    for (int o=0;o<16;++o){
      vx[o] = wxT[0*16+o]*p0 + wxT[1*16+o]*p1 + wxT[2*16+o]*p2
            + wxT[3*16+o]*q0 + wxT[4*16+o]*q1 + wxT[5*16+o]*q2;
    }
    #pragma unroll
    for (int o=0;o<16;++o){
      sf[o]+=y[o]; ssf[o]+=y[o]*y[o];
      sx[o]+=vx[o]; ssx[o]+=vx[o]*vx[o];
    }
    float* yt = ytmp + ((size_t)id*K_ + kk)*32;
    #pragma unroll
    for (int o=0;o<16;++o){ yt[o] = y[o]; yt[16+o] = vx[o]; }
  }
  #pragma unroll
  for (int o=0;o<16;++o){
    float v;
    v = wave_sum(sf[o]);  if ((threadIdx.x&63)==0) atomicAdd(&stats[SUM_F+o], v);
    v = wave_sum(ssf[o]); if ((threadIdx.x&63)==0) atomicAdd(&stats[SS_F+o], v);
    v = wave_sum(sx[o]);  if ((threadIdx.x&63)==0) atomicAdd(&stats[SUM_X+o], v);
    v = wave_sum(ssx[o]); if ((threadIdx.x&63)==0) atomicAdd(&stats[SS_X+o], v);
  }
}

// ---------------- finalize BN: scale/shift from sums ----------------
__global__ void k_finalize(float* stats, int sumoff, int ssoff, int nch, float cnt_inv,
                           const float* __restrict__ g, const float* __restrict__ bt,
                           int scoff, int shoff){
  int c = threadIdx.x;
  if (c < nch){
    float mean = stats[sumoff+c]*cnt_inv;
    float var  = stats[ssoff+c]*cnt_inv - mean*mean;
    float rstd = rsqrtf(var + EPS_);
    float sc = g[c]*rstd;
    stats[scoff+c] = sc;
    stats[shoff+c] = bt[c] - mean*sc;
  }
}

// ---------------- wprod apply: wp = lrelu(bn_f(y))*lrelu(bn_x(vx)) from ytmp ----------------
__global__ __launch_bounds__(256) void k_wapply(const float* __restrict__ ytmp, const float* __restrict__ stats,
                                                float* __restrict__ wprod){
  __shared__ float s4[64];   // scf[16] shf[16] scx[16] shx[16] (stats 2240..2304 contiguous)
  if (threadIdx.x < 64) s4[threadIdx.x] = stats[SCALE_F + threadIdx.x];
  __syncthreads();
  const int e = blockIdx.x*256 + threadIdx.x;   // < 327680
  const float* yt = ytmp + (size_t)e*32;
  float* wp = wprod + (size_t)e*16;
  #pragma unroll
  for (int o=0;o<16;++o){
    float a  = lrelu(yt[o]*s4[o] + s4[16+o]);
    float bb = lrelu(yt[16+o]*s4[32+o] + s4[48+o]);
    wp[o] = a*bb;
  }
}

// ---------------- a1 stats (conv 16->64 over wprod) ----------------
__global__ __launch_bounds__(256) void k_a1_stats(const float* __restrict__ wprod, const float* __restrict__ Wa1,
                                                  float* __restrict__ stats){
  __shared__ float wp[64*16];
  const int oc = threadIdx.x & 63, sub = threadIdx.x >> 6;
  float wa[16];
  #pragma unroll
  for (int j = 0; j < 16; ++j) wa[j] = Wa1[oc*16+j];
  float s = 0.f, ss = 0.f;
  for (int tile = blockIdx.x; tile < 5120; tile += gridDim.x){
    __syncthreads();
    for (int t = threadIdx.x; t < 1024; t += 256) wp[t] = wprod[(size_t)tile*1024 + t];
    __syncthreads();
    for (int p = sub*16; p < sub*16+16; ++p){
      float y = 0.f;
      #pragma unroll
      for (int j = 0; j < 16; ++j) y += wa[j]*wp[p*16+j];
      s += y; ss += y*y;
    }
  }
  atomicAdd(&stats[SUM_A1+oc], s);
  atomicAdd(&stats[SS_A1+oc], ss);
}

// ---------------- a2 Gram accumulate: S2 = Σ a1, G2 = Σ a1 a1^T over all (px,kk) ----------------
__global__ __launch_bounds__(256) void k_a2g(const float* __restrict__ wprod, const float* __restrict__ Wa1,
                                             const float* __restrict__ stats, float* __restrict__ aux){
  __shared__ float wp[64*16];
  __shared__ float a1t[64*64];
  __shared__ float wa1T[16*64];
  __shared__ float sc1[64], sh1[64];
  for (int t=threadIdx.x;t<1024;t+=256){ int j=t&63, jj=t>>6; wa1T[jj*64+j] = Wa1[j*16+jj]; }
  if (threadIdx.x < 64){ sc1[threadIdx.x]=stats[SCALE_A1+threadIdx.x]; sh1[threadIdx.x]=stats[SHIFT_A1+threadIdx.x]; }
  const int i  = threadIdx.x >> 2;   // 0..63: Gram row
  const int jq = threadIdx.x & 3;    // 0..3: 16-col quad
  f32x4 g0={0.f,0.f,0.f,0.f}, g1={0.f,0.f,0.f,0.f}, g2={0.f,0.f,0.f,0.f}, g3={0.f,0.f,0.f,0.f};
  float s = 0.f;
  for (int tile = blockIdx.x; tile < 5120; tile += gridDim.x){
    __syncthreads();
    for (int t=threadIdx.x;t<1024;t+=256) wp[t] = wprod[(size_t)tile*1024 + t];
    __syncthreads();
    for (int t=threadIdx.x;t<4096;t+=256){
      int p = t >> 6, j = t & 63;
      float yv=0.f;
      #pragma unroll
      for (int jj=0;jj<16;++jj) yv += wa1T[jj*64+j]*wp[p*16+jj];
      a1t[t] = lrelu(yv*sc1[j]+sh1[j]);
    }
    __syncthreads();
    #pragma unroll 4
    for (int p=0;p<64;++p){
      const float ai = a1t[p*64 + i];
      const f32x4* row = (const f32x4*)&a1t[p*64 + jq*16];
      g0 += ai*row[0]; g1 += ai*row[1]; g2 += ai*row[2]; g3 += ai*row[3];
      if (jq == 0) s += ai;
    }
  }
  float* G = aux + 64;
  const int base = i*64 + jq*16;
  #pragma unroll
  for (int r=0;r<4;++r){ atomicAdd(&G[base+r],    g0[r]); }
  #pragma unroll
  for (int r=0;r<4;++r){ atomicAdd(&G[base+4+r],  g1[r]); }
  #pragma unroll
  for (int r=0;r<4;++r){ atomicAdd(&G[base+8+r],  g2[r]); }
  #pragma unroll
  for (int r=0;r<4;++r){ atomicAdd(&G[base+12+r], g3[r]); }
  if (jq == 0) atomicAdd(&aux[i], s);
}

// ---------------- a2 finalize from Gram: SUM_A2 = w.S2, SS_A2 = w^T G2 w ----------------
__global__ void k_a2fin(const float* __restrict__ aux, const float* __restrict__ Wa2,
                        float* __restrict__ stats){
  __shared__ float G[4096];
  __shared__ float S[64];
  for (int t = threadIdx.x; t < 4096; t += 256) G[t] = aux[64 + t];
  if (threadIdx.x < 64) S[threadIdx.x] = aux[threadIdx.x];
  __syncthreads();
  const int oc = threadIdx.x;
  float w[64];
  #pragma unroll
  for (int j=0;j<64;++j) w[j] = Wa2[oc*64+j];
  float sum = 0.f;
  #pragma unroll
  for (int j=0;j<64;++j) sum += w[j]*S[j];
  float ss = 0.f;
  for (int i=0;i<64;++i){
    float gi = 0.f;
    #pragma unroll
    for (int j=0;j<64;++j) gi += w[j]*G[i*64+j];
    ss += w[i]*gi;
  }
  stats[SUM_A2+oc] = sum;
  stats[SS_A2+oc]  = ss;
}

// ---------------- prep Ai for conv_Wi t5-split GEMM ----------------
__global__ __launch_bounds__(256) void k_prepAi(const float* __restrict__ Wi, unsigned short* __restrict__ Ai){
  const int total = 512*896;
  for (int e = blockIdx.x*256 + threadIdx.x; e < total; e += gridDim.x*256){
    int o = e / 896, k = e - o*896;
    float v;
    if (k < 768){
      int u = k >> 7, c = k & 127;
      v = Wi[(size_t)o*1536 + (128+c)*6 + u];
    } else {
      const float* p = &Wi[(size_t)o*1536 + (size_t)(k-768)*6];
      v = p[0]+p[1]+p[2]+p[3]+p[4]+p[5];
    }
    Ai[e] = f2bf(v);
  }
}

// ---------------- prep A2 hi/lo for W2 refolded GEMM ----------------
__global__ __launch_bounds__(256) void k_prepA2(const float* __restrict__ W2,
                                                unsigned short* __restrict__ A2hi,
                                                unsigned short* __restrict__ A2lo){
  const int total = 256*KW2_;
  for (int e = blockIdx.x*256 + threadIdx.x; e < total; e += gridDim.x*256){
    int oc = e / KW2_, k = e - oc*KW2_;
    const float* wr = &W2[(size_t)oc*5120];
    float v;
    if (k < 2560){
      int o = k & 511, t5 = k >> 9;
      int cch = o >> 1, w = (o & 1)*5 + t5;
      v = wr[cch*20 + 10 + w];
    } else if (k < 3840){
      int kk = k - 2560; int w = kk >> 7, c = kk & 127;
      v = wr[(128+c)*20 + w];
    } else {
      int c = k - 3840;
      float s = 0.f;
      #pragma unroll
      for (int w = 0; w < 10; ++w) s += wr[c*20+w] - wr[(128+c)*20+w];
      v = s;
    }
    unsigned short hi = f2bf(v);
    float lo = v - bf2f(hi);
    A2hi[e] = hi;
    A2lo[e] = f2bf(lo);
  }
}

// ---------------- gather: Bd[pxl][slab*128+c] bf16, slabs 0..9 = diff(x_jw - x_self), 10 = self ----------------
__global__ __launch_bounds__(256) void k_gather(const float* __restrict__ xT, const int* __restrict__ idx,
                                                unsigned short* __restrict__ Bd, int pxbase){
  const int e = blockIdx.x*256 + threadIdx.x;   // < CHUNK_*16
  const int pxl = e >> 4, sub = e & 15;
  const int px = pxbase + pxl;
  const int c0 = sub*8;
  const float* xs = xT + (size_t)px*FIN_ + c0;
  const f32x4 s0 = *(const f32x4*)&xs[0];
  const f32x4 s1 = *(const f32x4*)&xs[4];
  unsigned short* bo = Bd + (size_t)pxl*1408;
  const size_t bb = (size_t)(px >> 11)*N_*FIN_;
  const int* ip = idx + (size_t)px*K_;
  #pragma unroll
  for (int w = 0; w < 10; ++w){
    int j = ip[w];
    const float* xj = xT + bb + (size_t)j*FIN_ + c0;
    const f32x4 a0 = *(const f32x4*)&xj[0];
    const f32x4 a1 = *(const f32x4*)&xj[4];
    unsigned short tw[8];
    tw[0]=f2bf(a0.x-s0.x); tw[1]=f2bf(a0.y-s0.y); tw[2]=f2bf(a0.z-s0.z); tw[3]=f2bf(a0.w-s0.w);
    tw[4]=f2bf(a1.x-s1.x); tw[5]=f2bf(a1.y-s1.y); tw[6]=f2bf(a1.z-s1.z); tw[7]=f2bf(a1.w-s1.w);
    *(s16x8*)&bo[w*128 + c0] = *(const s16x8*)tw;
  }
  unsigned short tw[8];
  tw[0]=f2bf(s0.x); tw[1]=f2bf(s0.y); tw[2]=f2bf(s0.z); tw[3]=f2bf(s0.w);
  tw[4]=f2bf(s1.x); tw[5]=f2bf(s1.y); tw[6]=f2bf(s1.z); tw[7]=f2bf(s1.w);
  *(s16x8*)&bo[1280 + c0] = *(const s16x8*)tw;
}

// ---------------- conv_Wi t5-split GEMM (bf16 MFMA), Bd-fed: per t5: C[512 x CHUNK] = Ai * B_t5 ----------------
__global__ __launch_bounds__(256) void k_gemmI(const unsigned short* __restrict__ Bd,
                                               const unsigned short* __restrict__ Ai,
                                               __hip_bfloat16* __restrict__ ybuf, float* __restrict__ stats,
                                               int pxbase){
  __shared__ __align__(16) unsigned short As[128*72];
  __shared__ __align__(16) unsigned short Bs[128*72];
  const int o0 = blockIdx.x * 128;     // 4 row tiles (o)
  const int c0 = blockIdx.y * 128;     // CHUNK_/128 col tiles (local px)
  const int t5 = blockIdx.z;           // 5
  const int rowA = threadIdx.x >> 1;
  const int kA   = (threadIdx.x & 1)*32;
  const unsigned short* arow = Ai + (size_t)(o0+rowA)*896 + kA;
  const int colJ = threadIdx.x >> 1;
  const int kB   = (threadIdx.x & 1)*32;
  const unsigned short* brow = Bd + (size_t)(c0 + colJ)*1408;
  const int wave = threadIdx.x >> 6, lane = threadIdx.x & 63;
  const int quad = lane >> 4, l16 = lane & 15;
  const int wm = wave & 1, wn = wave >> 1;

  f32x4 acc[4][4] = {};

  for (int k0 = 0; k0 < 896; k0 += 64){
    __syncthreads();
    {
      unsigned short* dst = &As[rowA*72 + kA];
      *(s16x8*)&dst[0]  = *(const s16x8*)&arow[k0+0];
      *(s16x8*)&dst[8]  = *(const s16x8*)&arow[k0+8];
      *(s16x8*)&dst[16] = *(const s16x8*)&arow[k0+16];
      *(s16x8*)&dst[24] = *(const s16x8*)&arow[k0+24];
    }
    {
      const int kk = k0 + kB;          // 32-aligned; band/self boundary (768) never splits a run
      const unsigned short* src = brow + ((kk < 768) ? ((t5 + (kk >> 7))*128 + (kk & 127))
                                                     : (1280 + (kk - 768)));
      unsigned short* dst = &Bs[colJ*72 + kB];
      *(s16x8*)&dst[0]  = *(const s16x8*)&src[0];
      *(s16x8*)&dst[8]  = *(const s16x8*)&src[8];
      *(s16x8*)&dst[16] = *(const s16x8*)&src[16];
      *(s16x8*)&dst[24] = *(const s16x8*)&src[24];
    }
    __syncthreads();
    #pragma unroll
    for (int ks = 0; ks < 2; ++ks){
      s16x8 af[4], bfr[4];
      #pragma unroll
      for (int mt = 0; mt < 4; ++mt)
        af[mt] = *(const s16x8*)&As[(wm*64 + mt*16 + l16)*72 + ks*32 + quad*8];
      #pragma unroll
      for (int nt = 0; nt < 4; ++nt)
        bfr[nt] = *(const s16x8*)&Bs[(wn*64 + nt*16 + l16)*72 + ks*32 + quad*8];
      #pragma unroll
      for (int mt = 0; mt < 4; ++mt)
        #pragma unroll
        for (int nt = 0; nt < 4; ++nt)
          acc[mt][nt] = __builtin_amdgcn_mfma_f32_16x16x32_bf16(af[mt], bfr[nt], acc[mt][nt], 0, 0, 0);
    }
  }

  __syncthreads();
  float* red = (float*)As;   // reuse (256 floats)
  red[threadIdx.x] = 0.f;
  __syncthreads();
  #pragma unroll
  for (int mt = 0; mt < 4; ++mt){
    const int rowLbase = wm*64 + mt*16 + quad*4;
    #pragma unroll
    for (int reg = 0; reg < 4; ++reg){
      float s = 0.f, ss = 0.f;
      #pragma unroll
      for (int nt = 0; nt < 4; ++nt){ float v = acc[mt][nt][reg]; s += v; ss += v*v; }
      atomicAdd(&red[(rowLbase+reg)*2+0], s);
      atomicAdd(&red[(rowLbase+reg)*2+1], ss);
    }
  }
  #pragma unroll
  for (int mt = 0; mt < 4; ++mt){
    #pragma unroll
    for (int nt = 0; nt < 4; ++nt){
      const int px = pxbase + c0 + wn*64 + nt*16 + l16;
      const int ob = wm*64 + mt*16 + quad*4;
      s16x4 w;
      #pragma unroll
      for (int reg = 0; reg < 4; ++reg) w[reg] = (short)f2bf(acc[mt][nt][reg]);
      *(s16x4*)&ybuf[(size_t)px*2560 + t5*512 + o0 + ob] = w;
    }
  }
  __syncthreads();
  if (threadIdx.x < 128){
    atomicAdd(&stats[SUM_I + o0 + threadIdx.x], red[threadIdx.x*2+0]);
    atomicAdd(&stats[SS_I + o0 + threadIdx.x], red[threadIdx.x*2+1]);
  }
}

// ---------------- w-chain + softmax + bn_i + interleave-multiply (in-place on ybuf, bf16) ----------------
// Persistent blocks: wa1T/sc/sh staged once, Wa2 row held in VGPRs (f32x4[16]); 16 px per block.
__global__ __launch_bounds__(256, 4) void k_wchain(const float* __restrict__ wprod, const float* __restrict__ Wa1,
                                                   const float* __restrict__ Wa2, const float* __restrict__ stats,
                                                   __hip_bfloat16* __restrict__ ybuf, int pxPerBlk){
  __shared__ float wp[160];
  __shared__ float a1l[640];
  __shared__ float wa1T[16*64];
  __shared__ float sc1[64], sh1[64];
  for (int t = threadIdx.x; t < 1024; t += 256){ int j = t & 63, jj = t >> 6; wa1T[jj*64+j] = Wa1[j*16+jj]; }
  if (threadIdx.x < 64){ sc1[threadIdx.x]=stats[SCALE_A1+threadIdx.x]; sh1[threadIdx.x]=stats[SHIFT_A1+threadIdx.x]; }
  const int c = threadIdx.x;
  f32x4 wa2v[16];
  #pragma unroll
  for (int j4=0;j4<16;++j4) wa2v[j4] = *(const f32x4*)&Wa2[c*64 + j4*4];
  const float sc2 = stats[SCALE_A2+c], sh2 = stats[SHIFT_A2+c];
  const float sci0 = stats[SCALE_I + 2*c], shi0 = stats[SHIFT_I + 2*c];
  const float sci1 = stats[SCALE_I + 2*c+1], shi1 = stats[SHIFT_I + 2*c+1];

  for (int pp = 0; pp < pxPerBlk; ++pp){
    const size_t px = (size_t)blockIdx.x*pxPerBlk + pp;
    __syncthreads();
    if (threadIdx.x < 160) wp[threadIdx.x] = wprod[px*160 + threadIdx.x];
    __syncthreads();
    for (int t = threadIdx.x; t < 640; t += 256){
      int kk = t >> 6, j = t & 63;
      float y=0.f;
      #pragma unroll
      for (int jj=0;jj<16;++jj) y += wa1T[jj*64+j]*wp[kk*16+jj];
      a1l[kk*64+j] = lrelu(y*sc1[j]+sh1[j]);
    }
    __syncthreads();
    float wt[10];
    #pragma unroll
    for (int kk=0;kk<10;++kk){
      f32x4 acc = {0.f,0.f,0.f,0.f};
      #pragma unroll
      for (int j4=0;j4<16;++j4){
        const f32x4 a = *(const f32x4*)&a1l[kk*64 + j4*4];
        acc += wa2v[j4]*a;
      }
      float y = (acc.x+acc.y)+(acc.z+acc.w);
      wt[kk] = lrelu(y*sc2+sh2);
    }
    float mx = wt[0];
    #pragma unroll
    for (int kk=1;kk<10;++kk) mx = fmaxf(mx, wt[kk]);
    float sum = 0.f;
    #pragma unroll
    for (int kk=0;kk<10;++kk){ wt[kk] = __expf(wt[kk]-mx); sum += wt[kk]; }
    float inv = 1.f/sum;
    __hip_bfloat16* yb = ybuf + px*2560;
    #pragma unroll
    for (int q = 0; q < 10; ++q){
      const int t5q = (q < 5) ? q : q-5;
      const int ii  = t5q*512 + 2*c + ((q < 5) ? 0 : 1);
      float v = __bfloat162float(yb[ii]);
      float sc = (q < 5) ? sci0 : sci1;
      float sh = (q < 5) ? shi0 : shi1;
      yb[ii] = __float2bfloat16(lrelu(v*sc+sh) * (wt[q]*inv));
    }
  }
}

// ---------------- W2 refolded GEMM (split-bf16 MFMA): outpre[256 x 32768]; fused o-stats ----------------
__global__ __launch_bounds__(256) void k_w2(const float* __restrict__ xT, const int* __restrict__ idx,
                                            const __hip_bfloat16* __restrict__ inte,
                                            const unsigned short* __restrict__ A2hi,
                                            const unsigned short* __restrict__ A2lo,
                                            float* __restrict__ outpre, float* __restrict__ stats){
  __shared__ __align__(16) unsigned short AsH[128*40];
  __shared__ __align__(16) unsigned short AsL[128*40];
  __shared__ __align__(16) unsigned short BsH[128*40];
  __shared__ __align__(16) unsigned short BsL[128*40];
  __shared__ int sIdx[128*10];
  const int r0 = blockIdx.x * 128;   // 2 row tiles (oc)
  const int c0 = blockIdx.y * 128;   // 256 col tiles (px)
  for (int t = threadIdx.x; t < 1280; t += 256) sIdx[t] = idx[(size_t)c0*10 + t];
  const int rowA  = threadIdx.x >> 1;
  const int halfA = threadIdx.x & 1;
  const unsigned short* ahrow = A2hi + (size_t)(r0+rowA)*KW2_ + halfA*16;
  const unsigned short* alrow = A2lo + (size_t)(r0+rowA)*KW2_ + halfA*16;
  const int colJ  = threadIdx.x >> 1;
  const int cHalf = (threadIdx.x & 1)*16;
  const int pxJ   = c0 + colJ;
  const size_t selfJ  = (size_t)pxJ*FIN_;
  const size_t bbaseJ = (size_t)(pxJ >> 11)*N_*FIN_;
  const __hip_bfloat16* ibJ = inte + (size_t)pxJ*2560;
  const int wave = threadIdx.x >> 6, lane = threadIdx.x & 63;
  const int quad = lane >> 4, l16 = lane & 15;
  const int wm = wave & 1, wn = wave >> 1;

  f32x4 acc[4][4] = {};

  for (int k0 = 0; k0 < KW2_; k0 += 32){
    __syncthreads();
    {
      *(s16x8*)&AsH[rowA*40 + halfA*16]     = *(const s16x8*)&ahrow[k0];
      *(s16x8*)&AsH[rowA*40 + halfA*16 + 8] = *(const s16x8*)&ahrow[k0+8];
      *(s16x8*)&AsL[rowA*40 + halfA*16]     = *(const s16x8*)&alrow[k0];
      *(s16x8*)&AsL[rowA*40 + halfA*16 + 8] = *(const s16x8*)&alrow[k0+8];
    }
    if (k0 < 2560){
      *(s16x8*)&BsH[colJ*40 + cHalf]     = *(const s16x8*)(ibJ + k0 + cHalf);
      *(s16x8*)&BsH[colJ*40 + cHalf + 8] = *(const s16x8*)(ibJ + k0 + cHalf + 8);
    } else {
      const float* src;
      if (k0 < 3840){
        const int w  = (k0 - 2560) >> 7;
        const int cb = ((k0 - 2560) & 127) + cHalf;
        const int j  = sIdx[colJ*10 + w];
        src = &xT[bbaseJ + (size_t)j*FIN_ + cb];
      } else {
        src = &xT[selfJ + (k0 - 3840) + cHalf];
      }
      unsigned short th[16], tl[16];
      #pragma unroll
      for (int q = 0; q < 4; ++q){
        const f32x4 v = *(const f32x4*)&src[q*4];
        #pragma unroll
        for (int e2 = 0; e2 < 4; ++e2){
          float f = v[e2];
          unsigned short h = f2bf(f);
          float r = f - bf2f(h);
          th[q*4+e2] = h;
          tl[q*4+e2] = f2bf(r);
        }
      }
      *(s16x8*)&BsH[colJ*40 + cHalf]     = *(const s16x8*)&th[0];
      *(s16x8*)&BsH[colJ*40 + cHalf + 8] = *(const s16x8*)&th[8];
      *(s16x8*)&BsL[colJ*40 + cHalf]     = *(const s16x8*)&tl[0];
      *(s16x8*)&BsL[colJ*40 + cHalf + 8] = *(const s16x8*)&tl[8];
    }
    __syncthreads();
    s16x8 ah[4], al[4], bh[4];
    #pragma unroll
    for (int mt = 0; mt < 4; ++mt){
      ah[mt] = *(const s16x8*)&AsH[(wm*64 + mt*16 + l16)*40 + quad*8];
      al[mt] = *(const s16x8*)&AsL[(wm*64 + mt*16 + l16)*40 + quad*8];
    }
    #pragma unroll
    for (int nt = 0; nt < 4; ++nt)
      bh[nt] = *(const s16x8*)&BsH[(wn*64 + nt*16 + l16)*40 + quad*8];
    #pragma unroll
    for (int mt = 0; mt < 4; ++mt)
      #pragma unroll
      for (int nt = 0; nt < 4; ++nt){
        acc[mt][nt] = __builtin_amdgcn_mfma_f32_16x16x32_bf16(ah[mt], bh[nt], acc[mt][nt], 0, 0, 0);
        acc[mt][nt] = __builtin_amdgcn_mfma_f32_16x16x32_bf16(al[mt], bh[nt], acc[mt][nt], 0, 0, 0);
      }
    if (k0 >= 2560){
      s16x8 bl[4];
      #pragma unroll
      for (int nt = 0; nt < 4; ++nt)
        bl[nt] = *(const s16x8*)&BsL[(wn*64 + nt*16 + l16)*40 + quad*8];
      #pragma unroll
      for (int mt = 0; mt < 4; ++mt)
        #pragma unroll
        for (int nt = 0; nt < 4; ++nt)
          acc[mt][nt] = __builtin_amdgcn_mfma_f32_16x16x32_bf16(ah[mt], bl[nt], acc[mt][nt], 0, 0, 0);
    }
  }

  __syncthreads();
  float* red = (float*)AsH;   // reuse (256 floats)
  red[threadIdx.x] = 0.f;
  __syncthreads();
  #pragma unroll
  for (int mt = 0; mt < 4; ++mt){
    const int rowLbase = wm*64 + mt*16 + quad*4;
    #pragma unroll
    for (int reg = 0; reg < 4; ++reg){
      float s = 0.f, ss = 0.f;
      #pragma unroll
      for (int nt = 0; nt < 4; ++nt){ float v = acc[mt][nt][reg]; s += v; ss += v*v; }
      atomicAdd(&red[(rowLbase+reg)*2+0], s);
      atomicAdd(&red[(rowLbase+reg)*2+1], ss);
    }
  }
  #pragma unroll
  for (int mt = 0; mt < 4; ++mt){
    #pragma unroll
    for (int nt = 0; nt < 4; ++nt){
      const int col = c0 + wn*64 + nt*16 + l16;
      const int rowb = r0 + wm*64 + mt*16 + quad*4;
      #pragma unroll
      for (int reg = 0; reg < 4; ++reg)
        outpre[(size_t)(rowb+reg)*32768 + col] = acc[mt][nt][reg];
    }
  }
  __syncthreads();
  if (threadIdx.x < 128){
    atomicAdd(&stats[SUM_O + r0 + threadIdx.x], red[threadIdx.x*2+0]);
    atomicAdd(&stats[SS_O + r0 + threadIdx.x], red[threadIdx.x*2+1]);
  }
}

// ---------------- final: bn2 + relu + reshape to [B,128,4096] ----------------
__global__ __launch_bounds__(256) void k_final(const float* __restrict__ outpre, const float* __restrict__ stats,
                                               float* __restrict__ out){
  const unsigned total = (unsigned)B_*128u*4096u;
  for (unsigned e = blockIdx.x*256u + threadIdx.x; e < total; e += gridDim.x*256u){
    unsigned b = e >> 19;
    unsigned rem = e & ((1u<<19)-1u);
    unsigned f = rem >> 12;
    unsigned m = rem & 4095u;
    unsigned half = m >> 11;
    unsigned n = m & 2047u;
    unsigned c = f*2u + half;
    float pre = outpre[(size_t)c*32768 + b*2048 + n];
    float v = pre*stats[SCALE_O+c] + stats[SHIFT_O+c];
    out[e] = fmaxf(v, 0.f);
  }
}

extern "C" void kernel_launch(void* const* d_in, const int* in_sizes, int n_in,
                              void* d_out, int out_size, void* d_ws, size_t ws_size,
                              hipStream_t stream) {
  (void)in_sizes; (void)n_in; (void)out_size;
  const float* x    = (const float*)d_in[0];
  const float* pc   = (const float*)d_in[1];
  const float* Wf   = (const float*)d_in[2];
  const float* gf   = (const float*)d_in[4];
  const float* btf  = (const float*)d_in[5];
  const float* Wx   = (const float*)d_in[6];
  const float* gx   = (const float*)d_in[8];
  const float* btx  = (const float*)d_in[9];
  const float* Wa1  = (const float*)d_in[10];
  const float* ga1  = (const float*)d_in[12];
  const float* bta1 = (const float*)d_in[13];
  const float* Wa2  = (const float*)d_in[14];
  const float* ga2  = (const float*)d_in[16];
  const float* bta2 = (const float*)d_in[17];
  const float* Wi   = (const float*)d_in[18];
  const float* gi   = (const float*)d_in[20];
  const float* bti  = (const float*)d_in[21];
  const float* W2   = (const float*)d_in[22];
  const float* g2   = (const float*)d_in[24];
  const float* bt2  = (const float*)d_in[25];
  float* out = (float*)d_out;

  char* ws = (char*)d_ws;
  float*  stats  = (float*)ws;                          //        0 ..    32768
  int*    idx    = (int*)  (ws + 32768);                //    32768 ..  1343488
  float*  sq     = (float*)(ws + 1343488);              //  1343488 ..  1605632 (uses first 131072)
  float*  aux    = (float*)(ws + 1474560);              //  S2[64]+G2[4096] in sq tail (dead after knn)
  float*  wprod  = (float*)(ws + 1605632);              //  1605632 .. 22577152
  float*  xT     = (float*)(ws + 22577152);             // 22577152 .. 39354368
  // A2hi/A2lo bf16 [256 x 3968] = 2,031,616 B each -> 39354368 .. 43417600
  unsigned short* A2hi = (unsigned short*)(ws + 39354368);
  unsigned short* A2lo = (unsigned short*)(ws + 41385984);
  float*  outpre = (float*)(ws + 44597248);             // 44597248 .. 78151680
  // Ai (bf16 [512x896] = 917,504 B) at 44597248..45514752; Bd chunk (bf16 [8192x1408] = 23,068,672 B)
  // at 45645824..68714496 — both inside outpre region, consumed before k_w2 writes outpre.
  unsigned short* Ai = (unsigned short*)(ws + 44597248);
  unsigned short* Bd = (unsigned short*)(ws + 45645824);
  __hip_bfloat16* ybuf = (__hip_bfloat16*)(ws + 78151680); // 78151680 .. 245923840
  // ytmp (fp32 [327680 x 32] = 41,943,040 B) overlaps ybuf: consumed by k_wapply before k_gemmI writes ybuf.
  float* ytmp = (float*)(ws + 78151680);
  if (ws_size < 245923840ULL) {
    fprintf(stderr, "kernel_launch: ws_size %zu < required 245923840\n", ws_size);
    return;
  }

  k_zero<<<1, 256, 0, stream>>>(stats, aux);
  k_xt<<<dim3(FIN_/32, N_/32, B_), 256, 0, stream>>>(x, xT);
  k_sq<<<(B_*N_)/256, 256, 0, stream>>>(x, sq);
  k_knn<<<dim3(N_/64, B_), 256, 0, stream>>>(x, sq, idx);
  k_prepAi<<<1024, 256, 0, stream>>>(Wi, Ai);
  k_prepA2<<<1024, 256, 0, stream>>>(W2, A2hi, A2lo);

  k_fx_stats<<<dim3((B_*N_)/256, 2), 256, 0, stream>>>(xT, pc, idx, Wf, Wx, stats, ytmp);
  k_finalize<<<1, 512, 0, stream>>>(stats, SUM_F, SS_F, 16, 1.f/327680.f, gf, btf, SCALE_F, SHIFT_F);
  k_finalize<<<1, 512, 0, stream>>>(stats, SUM_X, SS_X, 16, 1.f/327680.f, gx, btx, SCALE_X, SHIFT_X);

  k_wapply<<<1280, 256, 0, stream>>>(ytmp, stats, wprod);
  k_a1_stats<<<512, 256, 0, stream>>>(wprod, Wa1, stats);
  k_finalize<<<1, 512, 0, stream>>>(stats, SUM_A1, SS_A1, 64, 1.f/327680.f, ga1, bta1, SCALE_A1, SHIFT_A1);

  k_a2g<<<512, 256, 0, stream>>>(wprod, Wa1, stats, aux);
  k_a2fin<<<1, 256, 0, stream>>>(aux, Wa2, stats);
  k_finalize<<<1, 512, 0, stream>>>(stats, SUM_A2, SS_A2, 256, 1.f/327680.f, ga2, bta2, SCALE_A2, SHIFT_A2);

  for (int ch = 0; ch < (B_*N_)/CHUNK_; ++ch){
    k_gather<<<(CHUNK_*16)/256, 256, 0, stream>>>(xT, idx, Bd, ch*CHUNK_);
    k_gemmI<<<dim3(4, CHUNK_/128, 5), 256, 0, stream>>>(Bd, Ai, ybuf, stats, ch*CHUNK_);
  }
  k_finalize<<<1, 512, 0, stream>>>(stats, SUM_I, SS_I, 512, 1.f/163840.f, gi, bti, SCALE_I, SHIFT_I);

  k_wchain<<<2048, 256, 0, stream>>>(wprod, Wa1, Wa2, stats, ybuf, (B_*N_)/2048);

  k_w2<<<dim3(2, 256), 256, 0, stream>>>(xT, idx, ybuf, A2hi, A2lo, outpre, stats);
  k_finalize<<<1, 512, 0, stream>>>(stats, SUM_O, SS_O, 256, 1.f/32768.f, g2, bt2, SCALE_O, SHIFT_O);

  k_final<<<4096, 256, 0, stream>>>(outpre, stats, out);
}

// Round 13
// 2288.706 us; speedup vs baseline: 1.2362x; 1.0676x over previous
//
#include <hip/hip_runtime.h>
#include <hip/hip_bf16.h>
#include <cstdio>
#include <cstddef>

#define B_    16
#define FIN_  128
#define N_    2048
#define K_    10
#define EPS_  1e-5f
#define SLOPE_ 0.01f

typedef float f32x4 __attribute__((ext_vector_type(4)));
typedef short s16x8 __attribute__((ext_vector_type(8)));
typedef short s16x4 __attribute__((ext_vector_type(4)));

// ---- stats region layout (floats) ----
constexpr int SUM_F=0,   SS_F=16,   SUM_X=32,  SS_X=48;
constexpr int SUM_A1=64, SS_A1=128, SUM_A2=192,SS_A2=448;
constexpr int SUM_I=704, SS_I=1216, SUM_O=1728,SS_O=1984;
constexpr int SCALE_F=2240, SHIFT_F=2256, SCALE_X=2272, SHIFT_X=2288;
constexpr int SCALE_A1=2304, SHIFT_A1=2368, SCALE_A2=2432, SHIFT_A2=2688;
constexpr int SCALE_I=2944, SHIFT_I=3456, SCALE_O=3968, SHIFT_O=4224;
constexpr int STATS_TOTAL=4480;
// aux region (in sq tail): S2[64] + G2[64*64]
constexpr int AUX_TOTAL = 64 + 4096;

// W2 GEMM refolded K: [0,2560) inte, [2560,3840) band (w=(k-2560)>>7, c=k&127), [3840,3968) self
constexpr int KW2_ = 3968;
// gemmI px chunking (Bd scratch = CHUNK*1408*2 B = 23 MB)
constexpr int CHUNK_ = 8192;

__device__ __forceinline__ float lrelu(float v){ return v >= 0.f ? v : SLOPE_*v; }
__device__ __forceinline__ float wave_sum(float v){
  #pragma unroll
  for (int o = 32; o > 0; o >>= 1) v += __shfl_down(v, o, 64);
  return v;
}
__device__ __forceinline__ unsigned short f2bf(float f){
  __hip_bfloat16 h = __float2bfloat16(f);
  return *reinterpret_cast<unsigned short*>(&h);
}
__device__ __forceinline__ float bf2f(unsigned short u){
  __hip_bfloat16 h = *reinterpret_cast<__hip_bfloat16*>(&u);
  return __bfloat162float(h);
}

// ---------------- zero stats + aux ----------------
__global__ void k_zero(float* s, float* aux){
  for (int i = threadIdx.x; i < STATS_TOTAL; i += 256) s[i] = 0.f;
  for (int i = threadIdx.x; i < AUX_TOTAL; i += 256) aux[i] = 0.f;
}

// ---------------- transpose x -> xT [b][n][c] ----------------
__global__ __launch_bounds__(256) void k_xt(const float* __restrict__ x, float* __restrict__ xT){
  __shared__ float t[32][33];
  const int b = blockIdx.z;
  const int c0 = blockIdx.x*32, n0 = blockIdx.y*32;
  const int tx = threadIdx.x & 31, ty = threadIdx.x >> 5;
  #pragma unroll
  for (int s = 0; s < 32; s += 8)
    t[ty+s][tx] = x[((size_t)b*FIN_ + c0+ty+s)*N_ + n0 + tx];
  __syncthreads();
  #pragma unroll
  for (int s = 0; s < 32; s += 8)
    xT[((size_t)b*N_ + n0+ty+s)*FIN_ + c0 + tx] = t[tx][ty+s];
}

// ---------------- sq norms: XLA:CPU AVX-512 minor-dim reduce (MATCHED — do not change) ----------------
__global__ __launch_bounds__(256) void k_sq(const float* __restrict__ x, float* __restrict__ sq){
  int id = blockIdx.x*256 + threadIdx.x;      // < B_*N_
  int b = id >> 11, n = id & (N_-1);
  const float* xb = x + (size_t)b*FIN_*N_ + n;
  float part[16];
  #pragma unroll
  for (int p = 0; p < 16; ++p){
    float a = 0.f;
    #pragma unroll
    for (int q = 0; q < 8; ++q){
      float v = xb[(size_t)(p + 16*q)*N_];
      a = __fmaf_rn(v, v, a);
    }
    part[p] = a;
  }
  #pragma unroll
  for (int off = 8; off > 0; off >>= 1){
    #pragma unroll
    for (int l = 0; l < off; ++l)
      part[l] = __fadd_rn(part[l], part[l+off]);
  }
  sq[id] = part[0];
}

// ---------------- kNN: top-10 (excluding self) ----------------
// ROUND-6 VERIFIED VERSION (475us, VGPR 100, VALU 67%) — do not restructure.
__global__ __launch_bounds__(256, 2) void k_knn(const float* __restrict__ x, const float* __restrict__ sq,
                                                int* __restrict__ idx){
  __shared__ __align__(16) char smem[61440];
  float* xi = (float*)smem;   // [128][64] (32 KB), later reused as merge buffers
  const int b = blockIdx.y, i0 = blockIdx.x*64;
  const float* xb = x + (size_t)b*FIN_*N_;
  for (int t = threadIdx.x; t < FIN_*64; t += 256){
    int c = t >> 6, ii = t & 63;
    xi[t] = xb[(size_t)c*N_ + i0 + ii];
  }
  __syncthreads();
  const int ty = threadIdx.x >> 4;      // 0..15: i group (4 i's)
  const int tx = threadIdx.x & 15;      // 0..15: j group (4 j's per step)
  const int ibase = ty*4;
  const f32x4 sqi = *(const f32x4*)&sq[b*N_ + i0 + ibase];
  float bd[4][10]; int bi[4][10];
  #pragma unroll
  for (int ii=0;ii<4;++ii)
    #pragma unroll
    for (int s=0;s<10;++s){ bd[ii][s] = 1e30f; bi[ii][s] = -1; }

  for (int j0 = 0; j0 < N_; j0 += 64){
    const int jb = j0 + tx*4;
    const float* xjp = xb + jb;
    f32x4 acc[4] = {};    // acc[ii][m]
    #pragma unroll 8
    for (int c = 0; c < FIN_; ++c){
      const f32x4 a  = *(const f32x4*)&xi[c*64 + ibase];
      const f32x4 bb = *(const f32x4*)&xjp[(size_t)c*N_];
      #pragma unroll
      for (int ii=0;ii<4;++ii){
        #pragma unroll
        for (int m=0;m<4;++m)
          acc[ii][m] = __fmaf_rn(a[ii], bb[m], acc[ii][m]);
      }
    }
    const f32x4 sqj = *(const f32x4*)&sq[b*N_ + jb];
    #pragma unroll
    for (int ii=0;ii<4;++ii){
      const int i = i0 + ibase + ii;
      #pragma unroll
      for (int m=0;m<4;++m){
        int j = jb + m;
        float d = __fadd_rn(__fadd_rn(__fmul_rn(-2.f, acc[ii][m]), sqi[ii]), sqj[m]);
        if (j == i) d = 1e30f;
        if (d < bd[ii][9]){
          bd[ii][9] = d; bi[ii][9] = j;
          #pragma unroll
          for (int s = 9; s > 0; --s){
            if (bd[ii][s] < bd[ii][s-1]){
              float td = bd[ii][s]; bd[ii][s] = bd[ii][s-1]; bd[ii][s-1] = td;
              int ti = bi[ii][s]; bi[ii][s] = bi[ii][s-1]; bi[ii][s-1] = ti;
            }
          }
        }
      }
    }
  }

  __syncthreads();   // xi dead; reuse smem for merge buffers
  float* dbuf = (float*)smem;                               // [(list*10+s)*64 + ilocal] (40 KB)
  unsigned short* ibuf = (unsigned short*)(smem + 40960);   // same index (20 KB)
  #pragma unroll
  for (int ii=0;ii<4;++ii)
    #pragma unroll
    for (int s=0;s<10;++s){
      dbuf[(tx*10+s)*64 + ibase+ii] = bd[ii][s];
      ibuf[(tx*10+s)*64 + ibase+ii] = (unsigned short)bi[ii][s];
    }
  __syncthreads();
  if (threadIdx.x < 64){
    const int rr = threadIdx.x;
    int p[16];
    #pragma unroll
    for (int qq=0;qq<16;++qq) p[qq]=0;
    int* op = idx + ((size_t)b*N_ + i0 + rr)*K_;
    for (int s = 0; s < K_; ++s){
      float dm = 1e38f; int im = 0x7fffffff; int qm = 0;
      #pragma unroll
      for (int qq = 0; qq < 16; ++qq){
        int pq = p[qq];
        float d  = (pq < 10) ? dbuf[(qq*10+pq)*64 + rr] : 1e38f;
        int   jd = (pq < 10) ? (int)ibuf[(qq*10+pq)*64 + rr] : 0x7fffffff;
        bool take = (d < dm) || (d == dm && jd < im);
        if (take){ dm = d; im = jd; qm = qq; }
      }
      #pragma unroll
      for (int qq = 0; qq < 16; ++qq) if (qm == qq) p[qq]++;
      op[s] = im;
    }
  }
}

// ---------------- conv_f / conv_x stats (xT layout; also spills y/vx to ytmp) ----------------
// ROUND-10 VERIFIED VERSION (~345us): 1 thread/px, 10 compile-time-unrolled kk chains (the ILP
// carries this latency-bound kernel). R11 (runtime-strided kk: 865us) and R12 (grid.y=2 kk-split,
// 5 chains + 2x yc recompute: 503us) both regressed — do not restructure.
__global__ __launch_bounds__(256) void k_fx_stats(const float* __restrict__ xT, const float* __restrict__ pc,
                                                  const int* __restrict__ idx,
                                                  const float* __restrict__ Wf, const float* __restrict__ Wx,
                                                  float* __restrict__ stats, float* __restrict__ ytmp){
  __shared__ float wfT[256*16];
  __shared__ float wxT[6*16];
  for (int t = threadIdx.x; t < 256*16; t += 256){ int c = t >> 4, o = t & 15; wfT[t] = Wf[o*256 + c]; }
  if (threadIdx.x < 96){ int cc = threadIdx.x >> 4, o = threadIdx.x & 15; wxT[cc*16+o] = Wx[o*6+cc]; }
  __syncthreads();
  const int id = blockIdx.x*256 + threadIdx.x;
  const int b = id >> 11, n = id & (N_-1);
  const float* xs = xT + (size_t)id*FIN_;
  const float* pb = pc + (size_t)b*3*N_;
  float yc[16];
  #pragma unroll
  for (int o=0;o<16;++o) yc[o]=0.f;
  for (int c=0;c<FIN_;c+=4){
    const f32x4 v4 = *(const f32x4*)&xs[c];
    #pragma unroll
    for (int e=0;e<4;++e){
      float v = v4[e];
      #pragma unroll
      for (int o=0;o<16;++o) yc[o] += wfT[(c+e)*16+o]*v;
    }
  }
  float p0=pb[n], p1=pb[N_+n], p2=pb[2*N_+n];
  float sf[16], ssf[16], sx[16], ssx[16];
  #pragma unroll
  for (int o=0;o<16;++o){ sf[o]=0.f;ssf[o]=0.f;sx[o]=0.f;ssx[o]=0.f; }
  for (int kk=0;kk<K_;++kk){
    int j = idx[(size_t)id*K_ + kk];
    const float* xj = xT + ((size_t)b*N_ + j)*FIN_;
    float y[16];
    #pragma unroll
    for (int o=0;o<16;++o) y[o]=yc[o];
    for (int c=0;c<FIN_;c+=4){
      const f32x4 a4 = *(const f32x4*)&xj[c];
      const f32x4 s4 = *(const f32x4*)&xs[c];
      #pragma unroll
      for (int e=0;e<4;++e){
        float d = a4[e]-s4[e];
        #pragma unroll
        for (int o=0;o<16;++o) y[o] += wfT[(128+c+e)*16+o]*d;
      }
    }
    float q0=pb[j]-p0, q1=pb[N_+j]-p1, q2=pb[2*N_+j]-p2;
    float vx[16];
    #pragma unroll
    for (int o=0;o<16;++o){
      vx[o] = wxT[0*16+o]*p0 + wxT[1*16+o]*p1 + wxT[2*16+o]*p2
            + wxT[3*16+o]*q0 + wxT[4*16+o]*q1 + wxT[5*16+o]*q2;
    }
    #pragma unroll
    for (int o=0;o<16;++o){
      sf[o]+=y[o]; ssf[o]+=y[o]*y[o];
      sx[o]+=vx[o]; ssx[o]+=vx[o]*vx[o];
    }
    float* yt = ytmp + ((size_t)id*K_ + kk)*32;
    #pragma unroll
    for (int o=0;o<16;++o){ yt[o] = y[o]; yt[16+o] = vx[o]; }
  }
  #pragma unroll
  for (int o=0;o<16;++o){
    float v;
    v = wave_sum(sf[o]);  if ((threadIdx.x&63)==0) atomicAdd(&stats[SUM_F+o], v);
    v = wave_sum(ssf[o]); if ((threadIdx.x&63)==0) atomicAdd(&stats[SS_F+o], v);
    v = wave_sum(sx[o]);  if ((threadIdx.x&63)==0) atomicAdd(&stats[SUM_X+o], v);
    v = wave_sum(ssx[o]); if ((threadIdx.x&63)==0) atomicAdd(&stats[SS_X+o], v);
  }
}

// ---------------- finalize BN: scale/shift from sums ----------------
__global__ void k_finalize(float* stats, int sumoff, int ssoff, int nch, float cnt_inv,
                           const float* __restrict__ g, const float* __restrict__ bt,
                           int scoff, int shoff){
  int c = threadIdx.x;
  if (c < nch){
    float mean = stats[sumoff+c]*cnt_inv;
    float var  = stats[ssoff+c]*cnt_inv - mean*mean;
    float rstd = rsqrtf(var + EPS_);
    float sc = g[c]*rstd;
    stats[scoff+c] = sc;
    stats[shoff+c] = bt[c] - mean*sc;
  }
}

// ---------------- wprod apply: wp = lrelu(bn_f(y))*lrelu(bn_x(vx)) from ytmp ----------------
__global__ __launch_bounds__(256) void k_wapply(const float* __restrict__ ytmp, const float* __restrict__ stats,
                                                float* __restrict__ wprod){
  __shared__ float s4[64];   // scf[16] shf[16] scx[16] shx[16] (stats 2240..2304 contiguous)
  if (threadIdx.x < 64) s4[threadIdx.x] = stats[SCALE_F + threadIdx.x];
  __syncthreads();
  const int e = blockIdx.x*256 + threadIdx.x;   // < 327680
  const float* yt = ytmp + (size_t)e*32;
  float* wp = wprod + (size_t)e*16;
  #pragma unroll
  for (int o=0;o<16;++o){
    float a  = lrelu(yt[o]*s4[o] + s4[16+o]);
    float bb = lrelu(yt[16+o]*s4[32+o] + s4[48+o]);
    wp[o] = a*bb;
  }
}

// ---------------- a1 stats (conv 16->64 over wprod) ----------------
__global__ __launch_bounds__(256) void k_a1_stats(const float* __restrict__ wprod, const float* __restrict__ Wa1,
                                                  float* __restrict__ stats){
  __shared__ float wp[64*16];
  const int oc = threadIdx.x & 63, sub = threadIdx.x >> 6;
  float wa[16];
  #pragma unroll
  for (int j = 0; j < 16; ++j) wa[j] = Wa1[oc*16+j];
  float s = 0.f, ss = 0.f;
  for (int tile = blockIdx.x; tile < 5120; tile += gridDim.x){
    __syncthreads();
    for (int t = threadIdx.x; t < 1024; t += 256) wp[t] = wprod[(size_t)tile*1024 + t];
    __syncthreads();
    for (int p = sub*16; p < sub*16+16; ++p){
      float y = 0.f;
      #pragma unroll
      for (int j = 0; j < 16; ++j) y += wa[j]*wp[p*16+j];
      s += y; ss += y*y;
    }
  }
  atomicAdd(&stats[SUM_A1+oc], s);
  atomicAdd(&stats[SS_A1+oc], ss);
}

// ---------------- a2 Gram accumulate: S2 = Σ a1, G2 = Σ a1 a1^T over all (px,kk) ----------------
__global__ __launch_bounds__(256) void k_a2g(const float* __restrict__ wprod, const float* __restrict__ Wa1,
                                             const float* __restrict__ stats, float* __restrict__ aux){
  __shared__ float wp[64*16];
  __shared__ float a1t[64*64];
  __shared__ float wa1T[16*64];
  __shared__ float sc1[64], sh1[64];
  for (int t=threadIdx.x;t<1024;t+=256){ int j=t&63, jj=t>>6; wa1T[jj*64+j] = Wa1[j*16+jj]; }
  if (threadIdx.x < 64){ sc1[threadIdx.x]=stats[SCALE_A1+threadIdx.x]; sh1[threadIdx.x]=stats[SHIFT_A1+threadIdx.x]; }
  const int i  = threadIdx.x >> 2;   // 0..63: Gram row
  const int jq = threadIdx.x & 3;    // 0..3: 16-col quad
  f32x4 g0={0.f,0.f,0.f,0.f}, g1={0.f,0.f,0.f,0.f}, g2={0.f,0.f,0.f,0.f}, g3={0.f,0.f,0.f,0.f};
  float s = 0.f;
  for (int tile = blockIdx.x; tile < 5120; tile += gridDim.x){
    __syncthreads();
    for (int t=threadIdx.x;t<1024;t+=256) wp[t] = wprod[(size_t)tile*1024 + t];
    __syncthreads();
    for (int t=threadIdx.x;t<4096;t+=256){
      int p = t >> 6, j = t & 63;
      float yv=0.f;
      #pragma unroll
      for (int jj=0;jj<16;++jj) yv += wa1T[jj*64+j]*wp[p*16+jj];
      a1t[t] = lrelu(yv*sc1[j]+sh1[j]);
    }
    __syncthreads();
    #pragma unroll 4
    for (int p=0;p<64;++p){
      const float ai = a1t[p*64 + i];
      const f32x4* row = (const f32x4*)&a1t[p*64 + jq*16];
      g0 += ai*row[0]; g1 += ai*row[1]; g2 += ai*row[2]; g3 += ai*row[3];
      if (jq == 0) s += ai;
    }
  }
  float* G = aux + 64;
  const int base = i*64 + jq*16;
  #pragma unroll
  for (int r=0;r<4;++r){ atomicAdd(&G[base+r],    g0[r]); }
  #pragma unroll
  for (int r=0;r<4;++r){ atomicAdd(&G[base+4+r],  g1[r]); }
  #pragma unroll
  for (int r=0;r<4;++r){ atomicAdd(&G[base+8+r],  g2[r]); }
  #pragma unroll
  for (int r=0;r<4;++r){ atomicAdd(&G[base+12+r], g3[r]); }
  if (jq == 0) atomicAdd(&aux[i], s);
}

// ---------------- a2 finalize from Gram: SUM_A2 = w.S2, SS_A2 = w^T G2 w ----------------
__global__ void k_a2fin(const float* __restrict__ aux, const float* __restrict__ Wa2,
                        float* __restrict__ stats){
  __shared__ float G[4096];
  __shared__ float S[64];
  for (int t = threadIdx.x; t < 4096; t += 256) G[t] = aux[64 + t];
  if (threadIdx.x < 64) S[threadIdx.x] = aux[threadIdx.x];
  __syncthreads();
  const int oc = threadIdx.x;
  float w[64];
  #pragma unroll
  for (int j=0;j<64;++j) w[j] = Wa2[oc*64+j];
  float sum = 0.f;
  #pragma unroll
  for (int j=0;j<64;++j) sum += w[j]*S[j];
  float ss = 0.f;
  for (int i=0;i<64;++i){
    float gi = 0.f;
    #pragma unroll
    for (int j=0;j<64;++j) gi += w[j]*G[i*64+j];
    ss += w[i]*gi;
  }
  stats[SUM_A2+oc] = sum;
  stats[SS_A2+oc]  = ss;
}

// ---------------- prep Ai for conv_Wi t5-split GEMM ----------------
__global__ __launch_bounds__(256) void k_prepAi(const float* __restrict__ Wi, unsigned short* __restrict__ Ai){
  const int total = 512*896;
  for (int e = blockIdx.x*256 + threadIdx.x; e < total; e += gridDim.x*256){
    int o = e / 896, k = e - o*896;
    float v;
    if (k < 768){
      int u = k >> 7, c = k & 127;
      v = Wi[(size_t)o*1536 + (128+c)*6 + u];
    } else {
      const float* p = &Wi[(size_t)o*1536 + (size_t)(k-768)*6];
      v = p[0]+p[1]+p[2]+p[3]+p[4]+p[5];
    }
    Ai[e] = f2bf(v);
  }
}

// ---------------- prep A2 hi/lo for W2 refolded GEMM ----------------
__global__ __launch_bounds__(256) void k_prepA2(const float* __restrict__ W2,
                                                unsigned short* __restrict__ A2hi,
                                                unsigned short* __restrict__ A2lo){
  const int total = 256*KW2_;
  for (int e = blockIdx.x*256 + threadIdx.x; e < total; e += gridDim.x*256){
    int oc = e / KW2_, k = e - oc*KW2_;
    const float* wr = &W2[(size_t)oc*5120];
    float v;
    if (k < 2560){
      int o = k & 511, t5 = k >> 9;
      int cch = o >> 1, w = (o & 1)*5 + t5;
      v = wr[cch*20 + 10 + w];
    } else if (k < 3840){
      int kk = k - 2560; int w = kk >> 7, c = kk & 127;
      v = wr[(128+c)*20 + w];
    } else {
      int c = k - 3840;
      float s = 0.f;
      #pragma unroll
      for (int w = 0; w < 10; ++w) s += wr[c*20+w] - wr[(128+c)*20+w];
      v = s;
    }
    unsigned short hi = f2bf(v);
    float lo = v - bf2f(hi);
    A2hi[e] = hi;
    A2lo[e] = f2bf(lo);
  }
}

// ---------------- gather: Bd[pxl][slab*128+c] bf16, slabs 0..9 = diff(x_jw - x_self), 10 = self ----------------
__global__ __launch_bounds__(256) void k_gather(const float* __restrict__ xT, const int* __restrict__ idx,
                                                unsigned short* __restrict__ Bd, int pxbase){
  const int e = blockIdx.x*256 + threadIdx.x;   // < CHUNK_*16
  const int pxl = e >> 4, sub = e & 15;
  const int px = pxbase + pxl;
  const int c0 = sub*8;
  const float* xs = xT + (size_t)px*FIN_ + c0;
  const f32x4 s0 = *(const f32x4*)&xs[0];
  const f32x4 s1 = *(const f32x4*)&xs[4];
  unsigned short* bo = Bd + (size_t)pxl*1408;
  const size_t bb = (size_t)(px >> 11)*N_*FIN_;
  const int* ip = idx + (size_t)px*K_;
  #pragma unroll
  for (int w = 0; w < 10; ++w){
    int j = ip[w];
    const float* xj = xT + bb + (size_t)j*FIN_ + c0;
    const f32x4 a0 = *(const f32x4*)&xj[0];
    const f32x4 a1 = *(const f32x4*)&xj[4];
    unsigned short tw[8];
    tw[0]=f2bf(a0.x-s0.x); tw[1]=f2bf(a0.y-s0.y); tw[2]=f2bf(a0.z-s0.z); tw[3]=f2bf(a0.w-s0.w);
    tw[4]=f2bf(a1.x-s1.x); tw[5]=f2bf(a1.y-s1.y); tw[6]=f2bf(a1.z-s1.z); tw[7]=f2bf(a1.w-s1.w);
    *(s16x8*)&bo[w*128 + c0] = *(const s16x8*)tw;
  }
  unsigned short tw[8];
  tw[0]=f2bf(s0.x); tw[1]=f2bf(s0.y); tw[2]=f2bf(s0.z); tw[3]=f2bf(s0.w);
  tw[4]=f2bf(s1.x); tw[5]=f2bf(s1.y); tw[6]=f2bf(s1.z); tw[7]=f2bf(s1.w);
  *(s16x8*)&bo[1280 + c0] = *(const s16x8*)tw;
}

// ---------------- conv_Wi t5-split GEMM (bf16 MFMA), Bd-fed: per t5: C[512 x CHUNK] = Ai * B_t5 ----------------
__global__ __launch_bounds__(256) void k_gemmI(const unsigned short* __restrict__ Bd,
                                               const unsigned short* __restrict__ Ai,
                                               __hip_bfloat16* __restrict__ ybuf, float* __restrict__ stats,
                                               int pxbase){
  __shared__ __align__(16) unsigned short As[128*72];
  __shared__ __align__(16) unsigned short Bs[128*72];
  const int o0 = blockIdx.x * 128;     // 4 row tiles (o)
  const int c0 = blockIdx.y * 128;     // CHUNK_/128 col tiles (local px)
  const int t5 = blockIdx.z;           // 5
  const int rowA = threadIdx.x >> 1;
  const int kA   = (threadIdx.x & 1)*32;
  const unsigned short* arow = Ai + (size_t)(o0+rowA)*896 + kA;
  const int colJ = threadIdx.x >> 1;
  const int kB   = (threadIdx.x & 1)*32;
  const unsigned short* brow = Bd + (size_t)(c0 + colJ)*1408;
  const int wave = threadIdx.x >> 6, lane = threadIdx.x & 63;
  const int quad = lane >> 4, l16 = lane & 15;
  const int wm = wave & 1, wn = wave >> 1;

  f32x4 acc[4][4] = {};

  for (int k0 = 0; k0 < 896; k0 += 64){
    __syncthreads();
    {
      unsigned short* dst = &As[rowA*72 + kA];
      *(s16x8*)&dst[0]  = *(const s16x8*)&arow[k0+0];
      *(s16x8*)&dst[8]  = *(const s16x8*)&arow[k0+8];
      *(s16x8*)&dst[16] = *(const s16x8*)&arow[k0+16];
      *(s16x8*)&dst[24] = *(const s16x8*)&arow[k0+24];
    }
    {
      const int kk = k0 + kB;          // 32-aligned; band/self boundary (768) never splits a run
      const unsigned short* src = brow + ((kk < 768) ? ((t5 + (kk >> 7))*128 + (kk & 127))
                                                     : (1280 + (kk - 768)));
      unsigned short* dst = &Bs[colJ*72 + kB];
      *(s16x8*)&dst[0]  = *(const s16x8*)&src[0];
      *(s16x8*)&dst[8]  = *(const s16x8*)&src[8];
      *(s16x8*)&dst[16] = *(const s16x8*)&src[16];
      *(s16x8*)&dst[24] = *(const s16x8*)&src[24];
    }
    __syncthreads();
    #pragma unroll
    for (int ks = 0; ks < 2; ++ks){
      s16x8 af[4], bfr[4];
      #pragma unroll
      for (int mt = 0; mt < 4; ++mt)
        af[mt] = *(const s16x8*)&As[(wm*64 + mt*16 + l16)*72 + ks*32 + quad*8];
      #pragma unroll
      for (int nt = 0; nt < 4; ++nt)
        bfr[nt] = *(const s16x8*)&Bs[(wn*64 + nt*16 + l16)*72 + ks*32 + quad*8];
      #pragma unroll
      for (int mt = 0; mt < 4; ++mt)
        #pragma unroll
        for (int nt = 0; nt < 4; ++nt)
          acc[mt][nt] = __builtin_amdgcn_mfma_f32_16x16x32_bf16(af[mt], bfr[nt], acc[mt][nt], 0, 0, 0);
    }
  }

  __syncthreads();
  float* red = (float*)As;   // reuse (256 floats)
  red[threadIdx.x] = 0.f;
  __syncthreads();
  #pragma unroll
  for (int mt = 0; mt < 4; ++mt){
    const int rowLbase = wm*64 + mt*16 + quad*4;
    #pragma unroll
    for (int reg = 0; reg < 4; ++reg){
      float s = 0.f, ss = 0.f;
      #pragma unroll
      for (int nt = 0; nt < 4; ++nt){ float v = acc[mt][nt][reg]; s += v; ss += v*v; }
      atomicAdd(&red[(rowLbase+reg)*2+0], s);
      atomicAdd(&red[(rowLbase+reg)*2+1], ss);
    }
  }
  #pragma unroll
  for (int mt = 0; mt < 4; ++mt){
    #pragma unroll
    for (int nt = 0; nt < 4; ++nt){
      const int px = pxbase + c0 + wn*64 + nt*16 + l16;
      const int ob = wm*64 + mt*16 + quad*4;
      s16x4 w;
      #pragma unroll
      for (int reg = 0; reg < 4; ++reg) w[reg] = (short)f2bf(acc[mt][nt][reg]);
      *(s16x4*)&ybuf[(size_t)px*2560 + t5*512 + o0 + ob] = w;
    }
  }
  __syncthreads();
  if (threadIdx.x < 128){
    atomicAdd(&stats[SUM_I + o0 + threadIdx.x], red[threadIdx.x*2+0]);
    atomicAdd(&stats[SS_I + o0 + threadIdx.x], red[threadIdx.x*2+1]);
  }
}

// ---------------- w-chain + softmax + bn_i + interleave-multiply (in-place on ybuf, bf16) ----------------
// Persistent blocks: wa1T/sc/sh staged once, Wa2 row held in VGPRs (f32x4[16]); 16 px per block.
__global__ __launch_bounds__(256, 4) void k_wchain(const float* __restrict__ wprod, const float* __restrict__ Wa1,
                                                   const float* __restrict__ Wa2, const float* __restrict__ stats,
                                                   __hip_bfloat16* __restrict__ ybuf, int pxPerBlk){
  __shared__ float wp[160];
  __shared__ float a1l[640];
  __shared__ float wa1T[16*64];
  __shared__ float sc1[64], sh1[64];
  for (int t = threadIdx.x; t < 1024; t += 256){ int j = t & 63, jj = t >> 6; wa1T[jj*64+j] = Wa1[j*16+jj]; }
  if (threadIdx.x < 64){ sc1[threadIdx.x]=stats[SCALE_A1+threadIdx.x]; sh1[threadIdx.x]=stats[SHIFT_A1+threadIdx.x]; }
  const int c = threadIdx.x;
  f32x4 wa2v[16];
  #pragma unroll
  for (int j4=0;j4<16;++j4) wa2v[j4] = *(const f32x4*)&Wa2[c*64 + j4*4];
  const float sc2 = stats[SCALE_A2+c], sh2 = stats[SHIFT_A2+c];
  const float sci0 = stats[SCALE_I + 2*c], shi0 = stats[SHIFT_I + 2*c];
  const float sci1 = stats[SCALE_I + 2*c+1], shi1 = stats[SHIFT_I + 2*c+1];

  for (int pp = 0; pp < pxPerBlk; ++pp){
    const size_t px = (size_t)blockIdx.x*pxPerBlk + pp;
    __syncthreads();
    if (threadIdx.x < 160) wp[threadIdx.x] = wprod[px*160 + threadIdx.x];
    __syncthreads();
    for (int t = threadIdx.x; t < 640; t += 256){
      int kk = t >> 6, j = t & 63;
      float y=0.f;
      #pragma unroll
      for (int jj=0;jj<16;++jj) y += wa1T[jj*64+j]*wp[kk*16+jj];
      a1l[kk*64+j] = lrelu(y*sc1[j]+sh1[j]);
    }
    __syncthreads();
    float wt[10];
    #pragma unroll
    for (int kk=0;kk<10;++kk){
      f32x4 acc = {0.f,0.f,0.f,0.f};
      #pragma unroll
      for (int j4=0;j4<16;++j4){
        const f32x4 a = *(const f32x4*)&a1l[kk*64 + j4*4];
        acc += wa2v[j4]*a;
      }
      float y = (acc.x+acc.y)+(acc.z+acc.w);
      wt[kk] = lrelu(y*sc2+sh2);
    }
    float mx = wt[0];
    #pragma unroll
    for (int kk=1;kk<10;++kk) mx = fmaxf(mx, wt[kk]);
    float sum = 0.f;
    #pragma unroll
    for (int kk=0;kk<10;++kk){ wt[kk] = __expf(wt[kk]-mx); sum += wt[kk]; }
    float inv = 1.f/sum;
    __hip_bfloat16* yb = ybuf + px*2560;
    #pragma unroll
    for (int q = 0; q < 10; ++q){
      const int t5q = (q < 5) ? q : q-5;
      const int ii  = t5q*512 + 2*c + ((q < 5) ? 0 : 1);
      float v = __bfloat162float(yb[ii]);
      float sc = (q < 5) ? sci0 : sci1;
      float sh = (q < 5) ? shi0 : shi1;
      yb[ii] = __float2bfloat16(lrelu(v*sc+sh) * (wt[q]*inv));
    }
  }
}

// ---------------- W2 refolded GEMM (split-bf16 MFMA): outpre[256 x 32768]; fused o-stats ----------------
__global__ __launch_bounds__(256) void k_w2(const float* __restrict__ xT, const int* __restrict__ idx,
                                            const __hip_bfloat16* __restrict__ inte,
                                            const unsigned short* __restrict__ A2hi,
                                            const unsigned short* __restrict__ A2lo,
                                            float* __restrict__ outpre, float* __restrict__ stats){
  __shared__ __align__(16) unsigned short AsH[128*40];
  __shared__ __align__(16) unsigned short AsL[128*40];
  __shared__ __align__(16) unsigned short BsH[128*40];
  __shared__ __align__(16) unsigned short BsL[128*40];
  __shared__ int sIdx[128*10];
  const int r0 = blockIdx.x * 128;   // 2 row tiles (oc)
  const int c0 = blockIdx.y * 128;   // 256 col tiles (px)
  for (int t = threadIdx.x; t < 1280; t += 256) sIdx[t] = idx[(size_t)c0*10 + t];
  const int rowA  = threadIdx.x >> 1;
  const int halfA = threadIdx.x & 1;
  const unsigned short* ahrow = A2hi + (size_t)(r0+rowA)*KW2_ + halfA*16;
  const unsigned short* alrow = A2lo + (size_t)(r0+rowA)*KW2_ + halfA*16;
  const int colJ  = threadIdx.x >> 1;
  const int cHalf = (threadIdx.x & 1)*16;
  const int pxJ   = c0 + colJ;
  const size_t selfJ  = (size_t)pxJ*FIN_;
  const size_t bbaseJ = (size_t)(pxJ >> 11)*N_*FIN_;
  const __hip_bfloat16* ibJ = inte + (size_t)pxJ*2560;
  const int wave = threadIdx.x >> 6, lane = threadIdx.x & 63;
  const int quad = lane >> 4, l16 = lane & 15;
  const int wm = wave & 1, wn = wave >> 1;

  f32x4 acc[4][4] = {};

  for (int k0 = 0; k0 < KW2_; k0 += 32){
    __syncthreads();
    {
      *(s16x8*)&AsH[rowA*40 + halfA*16]     = *(const s16x8*)&ahrow[k0];
      *(s16x8*)&AsH[rowA*40 + halfA*16 + 8] = *(const s16x8*)&ahrow[k0+8];
      *(s16x8*)&AsL[rowA*40 + halfA*16]     = *(const s16x8*)&alrow[k0];
      *(s16x8*)&AsL[rowA*40 + halfA*16 + 8] = *(const s16x8*)&alrow[k0+8];
    }
    if (k0 < 2560){
      *(s16x8*)&BsH[colJ*40 + cHalf]     = *(const s16x8*)(ibJ + k0 + cHalf);
      *(s16x8*)&BsH[colJ*40 + cHalf + 8] = *(const s16x8*)(ibJ + k0 + cHalf + 8);
    } else {
      const float* src;
      if (k0 < 3840){
        const int w  = (k0 - 2560) >> 7;
        const int cb = ((k0 - 2560) & 127) + cHalf;
        const int j  = sIdx[colJ*10 + w];
        src = &xT[bbaseJ + (size_t)j*FIN_ + cb];
      } else {
        src = &xT[selfJ + (k0 - 3840) + cHalf];
      }
      unsigned short th[16], tl[16];
      #pragma unroll
      for (int q = 0; q < 4; ++q){
        const f32x4 v = *(const f32x4*)&src[q*4];
        #pragma unroll
        for (int e2 = 0; e2 < 4; ++e2){
          float f = v[e2];
          unsigned short h = f2bf(f);
          float r = f - bf2f(h);
          th[q*4+e2] = h;
          tl[q*4+e2] = f2bf(r);
        }
      }
      *(s16x8*)&BsH[colJ*40 + cHalf]     = *(const s16x8*)&th[0];
      *(s16x8*)&BsH[colJ*40 + cHalf + 8] = *(const s16x8*)&th[8];
      *(s16x8*)&BsL[colJ*40 + cHalf]     = *(const s16x8*)&tl[0];
      *(s16x8*)&BsL[colJ*40 + cHalf + 8] = *(const s16x8*)&tl[8];
    }
    __syncthreads();
    s16x8 ah[4], al[4], bh[4];
    #pragma unroll
    for (int mt = 0; mt < 4; ++mt){
      ah[mt] = *(const s16x8*)&AsH[(wm*64 + mt*16 + l16)*40 + quad*8];
      al[mt] = *(const s16x8*)&AsL[(wm*64 + mt*16 + l16)*40 + quad*8];
    }
    #pragma unroll
    for (int nt = 0; nt < 4; ++nt)
      bh[nt] = *(const s16x8*)&BsH[(wn*64 + nt*16 + l16)*40 + quad*8];
    #pragma unroll
    for (int mt = 0; mt < 4; ++mt)
      #pragma unroll
      for (int nt = 0; nt < 4; ++nt){
        acc[mt][nt] = __builtin_amdgcn_mfma_f32_16x16x32_bf16(ah[mt], bh[nt], acc[mt][nt], 0, 0, 0);
        acc[mt][nt] = __builtin_amdgcn_mfma_f32_16x16x32_bf16(al[mt], bh[nt], acc[mt][nt], 0, 0, 0);
      }
    if (k0 >= 2560){
      s16x8 bl[4];
      #pragma unroll
      for (int nt = 0; nt < 4; ++nt)
        bl[nt] = *(const s16x8*)&BsL[(wn*64 + nt*16 + l16)*40 + quad*8];
      #pragma unroll
      for (int mt = 0; mt < 4; ++mt)
        #pragma unroll
        for (int nt = 0; nt < 4; ++nt)
          acc[mt][nt] = __builtin_amdgcn_mfma_f32_16x16x32_bf16(ah[mt], bl[nt], acc[mt][nt], 0, 0, 0);
    }
  }

  __syncthreads();
  float* red = (float*)AsH;   // reuse (256 floats)
  red[threadIdx.x] = 0.f;
  __syncthreads();
  #pragma unroll
  for (int mt = 0; mt < 4; ++mt){
    const int rowLbase = wm*64 + mt*16 + quad*4;
    #pragma unroll
    for (int reg = 0; reg < 4; ++reg){
      float s = 0.f, ss = 0.f;
      #pragma unroll
      for (int nt = 0; nt < 4; ++nt){ float v = acc[mt][nt][reg]; s += v; ss += v*v; }
      atomicAdd(&red[(rowLbase+reg)*2+0], s);
      atomicAdd(&red[(rowLbase+reg)*2+1], ss);
    }
  }
  #pragma unroll
  for (int mt = 0; mt < 4; ++mt){
    #pragma unroll
    for (int nt = 0; nt < 4; ++nt){
      const int col = c0 + wn*64 + nt*16 + l16;
      const int rowb = r0 + wm*64 + mt*16 + quad*4;
      #pragma unroll
      for (int reg = 0; reg < 4; ++reg)
        outpre[(size_t)(rowb+reg)*32768 + col] = acc[mt][nt][reg];
    }
  }
  __syncthreads();
  if (threadIdx.x < 128){
    atomicAdd(&stats[SUM_O + r0 + threadIdx.x], red[threadIdx.x*2+0]);
    atomicAdd(&stats[SS_O + r0 + threadIdx.x], red[threadIdx.x*2+1]);
  }
}

// ---------------- final: bn2 + relu + reshape to [B,128,4096] ----------------
__global__ __launch_bounds__(256) void k_final(const float* __restrict__ outpre, const float* __restrict__ stats,
                                               float* __restrict__ out){
  const unsigned total = (unsigned)B_*128u*4096u;
  for (unsigned e = blockIdx.x*256u + threadIdx.x; e < total; e += gridDim.x*256u){
    unsigned b = e >> 19;
    unsigned rem = e & ((1u<<19)-1u);
    unsigned f = rem >> 12;
    unsigned m = rem & 4095u;
    unsigned half = m >> 11;
    unsigned n = m & 2047u;
    unsigned c = f*2u + half;
    float pre = outpre[(size_t)c*32768 + b*2048 + n];
    float v = pre*stats[SCALE_O+c] + stats[SHIFT_O+c];
    out[e] = fmaxf(v, 0.f);
  }
}

extern "C" void kernel_launch(void* const* d_in, const int* in_sizes, int n_in,
                              void* d_out, int out_size, void* d_ws, size_t ws_size,
                              hipStream_t stream) {
  (void)in_sizes; (void)n_in; (void)out_size;
  const float* x    = (const float*)d_in[0];
  const float* pc   = (const float*)d_in[1];
  const float* Wf   = (const float*)d_in[2];
  const float* gf   = (const float*)d_in[4];
  const float* btf  = (const float*)d_in[5];
  const float* Wx   = (const float*)d_in[6];
  const float* gx   = (const float*)d_in[8];
  const float* btx  = (const float*)d_in[9];
  const float* Wa1  = (const float*)d_in[10];
  const float* ga1  = (const float*)d_in[12];
  const float* bta1 = (const float*)d_in[13];
  const float* Wa2  = (const float*)d_in[14];
  const float* ga2  = (const float*)d_in[16];
  const float* bta2 = (const float*)d_in[17];
  const float* Wi   = (const float*)d_in[18];
  const float* gi   = (const float*)d_in[20];
  const float* bti  = (const float*)d_in[21];
  const float* W2   = (const float*)d_in[22];
  const float* g2   = (const float*)d_in[24];
  const float* bt2  = (const float*)d_in[25];
  float* out = (float*)d_out;

  char* ws = (char*)d_ws;
  float*  stats  = (float*)ws;                          //        0 ..    32768
  int*    idx    = (int*)  (ws + 32768);                //    32768 ..  1343488
  float*  sq     = (float*)(ws + 1343488);              //  1343488 ..  1605632 (uses first 131072)
  float*  aux    = (float*)(ws + 1474560);              //  S2[64]+G2[4096] in sq tail (dead after knn)
  float*  wprod  = (float*)(ws + 1605632);              //  1605632 .. 22577152
  float*  xT     = (float*)(ws + 22577152);             // 22577152 .. 39354368
  // A2hi/A2lo bf16 [256 x 3968] = 2,031,616 B each -> 39354368 .. 43417600
  unsigned short* A2hi = (unsigned short*)(ws + 39354368);
  unsigned short* A2lo = (unsigned short*)(ws + 41385984);
  float*  outpre = (float*)(ws + 44597248);             // 44597248 .. 78151680
  // Ai (bf16 [512x896] = 917,504 B) at 44597248..45514752; Bd chunk (bf16 [8192x1408] = 23,068,672 B)
  // at 45645824..68714496 — both inside outpre region, consumed before k_w2 writes outpre.
  unsigned short* Ai = (unsigned short*)(ws + 44597248);
  unsigned short* Bd = (unsigned short*)(ws + 45645824);
  __hip_bfloat16* ybuf = (__hip_bfloat16*)(ws + 78151680); // 78151680 .. 245923840
  // ytmp (fp32 [327680 x 32] = 41,943,040 B) overlaps ybuf: consumed by k_wapply before k_gemmI writes ybuf.
  float* ytmp = (float*)(ws + 78151680);
  if (ws_size < 245923840ULL) {
    fprintf(stderr, "kernel_launch: ws_size %zu < required 245923840\n", ws_size);
    return;
  }

  k_zero<<<1, 256, 0, stream>>>(stats, aux);
  k_xt<<<dim3(FIN_/32, N_/32, B_), 256, 0, stream>>>(x, xT);
  k_sq<<<(B_*N_)/256, 256, 0, stream>>>(x, sq);
  k_knn<<<dim3(N_/64, B_), 256, 0, stream>>>(x, sq, idx);
  k_prepAi<<<1024, 256, 0, stream>>>(Wi, Ai);
  k_prepA2<<<1024, 256, 0, stream>>>(W2, A2hi, A2lo);

  k_fx_stats<<<(B_*N_)/256, 256, 0, stream>>>(xT, pc, idx, Wf, Wx, stats, ytmp);
  k_finalize<<<1, 512, 0, stream>>>(stats, SUM_F, SS_F, 16, 1.f/327680.f, gf, btf, SCALE_F, SHIFT_F);
  k_finalize<<<1, 512, 0, stream>>>(stats, SUM_X, SS_X, 16, 1.f/327680.f, gx, btx, SCALE_X, SHIFT_X);

  k_wapply<<<1280, 256, 0, stream>>>(ytmp, stats, wprod);
  k_a1_stats<<<512, 256, 0, stream>>>(wprod, Wa1, stats);
  k_finalize<<<1, 512, 0, stream>>>(stats, SUM_A1, SS_A1, 64, 1.f/327680.f, ga1, bta1, SCALE_A1, SHIFT_A1);

  k_a2g<<<512, 256, 0, stream>>>(wprod, Wa1, stats, aux);
  k_a2fin<<<1, 256, 0, stream>>>(aux, Wa2, stats);
  k_finalize<<<1, 512, 0, stream>>>(stats, SUM_A2, SS_A2, 256, 1.f/327680.f, ga2, bta2, SCALE_A2, SHIFT_A2);

  for (int ch = 0; ch < (B_*N_)/CHUNK_; ++ch){
    k_gather<<<(CHUNK_*16)/256, 256, 0, stream>>>(xT, idx, Bd, ch*CHUNK_);
    k_gemmI<<<dim3(4, CHUNK_/128, 5), 256, 0, stream>>>(Bd, Ai, ybuf, stats, ch*CHUNK_);
  }
  k_finalize<<<1, 512, 0, stream>>>(stats, SUM_I, SS_I, 512, 1.f/163840.f, gi, bti, SCALE_I, SHIFT_I);

  k_wchain<<<2048, 256, 0, stream>>>(wprod, Wa1, Wa2, stats, ybuf, (B_*N_)/2048);

  k_w2<<<dim3(2, 256), 256, 0, stream>>>(xT, idx, ybuf, A2hi, A2lo, outpre, stats);
  k_finalize<<<1, 512, 0, stream>>>(stats, SUM_O, SS_O, 256, 1.f/32768.f, g2, bt2, SCALE_O, SHIFT_O);

  k_final<<<4096, 256, 0, stream>>>(outpre, stats, out);
}

// Round 14
// 2206.748 us; speedup vs baseline: 1.2822x; 1.0371x over previous
//
#include <hip/hip_runtime.h>
#include <hip/hip_bf16.h>
#include <cstdio>
#include <cstddef>

#define B_    16
#define FIN_  128
#define N_    2048
#define K_    10
#define EPS_  1e-5f
#define SLOPE_ 0.01f

typedef float f32x4 __attribute__((ext_vector_type(4)));
typedef short s16x8 __attribute__((ext_vector_type(8)));
typedef short s16x4 __attribute__((ext_vector_type(4)));

// ---- stats region layout (floats) ----
constexpr int SUM_F=0,   SS_F=16,   SUM_X=32,  SS_X=48;
constexpr int SUM_A1=64, SS_A1=128, SUM_A2=192,SS_A2=448;
constexpr int SUM_I=704, SS_I=1216, SUM_O=1728,SS_O=1984;
constexpr int SCALE_F=2240, SHIFT_F=2256, SCALE_X=2272, SHIFT_X=2288;
constexpr int SCALE_A1=2304, SHIFT_A1=2368, SCALE_A2=2432, SHIFT_A2=2688;
constexpr int SCALE_I=2944, SHIFT_I=3456, SCALE_O=3968, SHIFT_O=4224;
constexpr int STATS_TOTAL=4480;
// aux region (in sq tail): S2[64] + G2[64*64]
constexpr int AUX_TOTAL = 64 + 4096;

// W2 GEMM refolded K: [0,2560) inte, [2560,3840) band (w=(k-2560)>>7, c=k&127), [3840,3968) self
constexpr int KW2_ = 3968;
// gemmI px chunking (Bd scratch = CHUNK*1408*2 B = 23 MB)
constexpr int CHUNK_ = 8192;

__device__ __forceinline__ float lrelu(float v){ return v >= 0.f ? v : SLOPE_*v; }
__device__ __forceinline__ float wave_sum(float v){
  #pragma unroll
  for (int o = 32; o > 0; o >>= 1) v += __shfl_down(v, o, 64);
  return v;
}
__device__ __forceinline__ unsigned short f2bf(float f){
  __hip_bfloat16 h = __float2bfloat16(f);
  return *reinterpret_cast<unsigned short*>(&h);
}
__device__ __forceinline__ float bf2f(unsigned short u){
  __hip_bfloat16 h = *reinterpret_cast<__hip_bfloat16*>(&u);
  return __bfloat162float(h);
}

// ---------------- zero stats + aux ----------------
__global__ void k_zero(float* s, float* aux){
  for (int i = threadIdx.x; i < STATS_TOTAL; i += 256) s[i] = 0.f;
  for (int i = threadIdx.x; i < AUX_TOTAL; i += 256) aux[i] = 0.f;
}

// ---------------- transpose x -> xT [b][n][c] ----------------
__global__ __launch_bounds__(256) void k_xt(const float* __restrict__ x, float* __restrict__ xT){
  __shared__ float t[32][33];
  const int b = blockIdx.z;
  const int c0 = blockIdx.x*32, n0 = blockIdx.y*32;
  const int tx = threadIdx.x & 31, ty = threadIdx.x >> 5;
  #pragma unroll
  for (int s = 0; s < 32; s += 8)
    t[ty+s][tx] = x[((size_t)b*FIN_ + c0+ty+s)*N_ + n0 + tx];
  __syncthreads();
  #pragma unroll
  for (int s = 0; s < 32; s += 8)
    xT[((size_t)b*N_ + n0+ty+s)*FIN_ + c0 + tx] = t[tx][ty+s];
}

// ---------------- sq norms: XLA:CPU AVX-512 minor-dim reduce (MATCHED — do not change) ----------------
__global__ __launch_bounds__(256) void k_sq(const float* __restrict__ x, float* __restrict__ sq){
  int id = blockIdx.x*256 + threadIdx.x;      // < B_*N_
  int b = id >> 11, n = id & (N_-1);
  const float* xb = x + (size_t)b*FIN_*N_ + n;
  float part[16];
  #pragma unroll
  for (int p = 0; p < 16; ++p){
    float a = 0.f;
    #pragma unroll
    for (int q = 0; q < 8; ++q){
      float v = xb[(size_t)(p + 16*q)*N_];
      a = __fmaf_rn(v, v, a);
    }
    part[p] = a;
  }
  #pragma unroll
  for (int off = 8; off > 0; off >>= 1){
    #pragma unroll
    for (int l = 0; l < off; ++l)
      part[l] = __fadd_rn(part[l], part[l+off]);
  }
  sq[id] = part[0];
}

// ---------------- kNN: top-10 (excluding self) ----------------
// ROUND-6 VERIFIED VERSION (475us, VGPR 100, VALU 67%) — do not restructure.
__global__ __launch_bounds__(256, 2) void k_knn(const float* __restrict__ x, const float* __restrict__ sq,
                                                int* __restrict__ idx){
  __shared__ __align__(16) char smem[61440];
  float* xi = (float*)smem;   // [128][64] (32 KB), later reused as merge buffers
  const int b = blockIdx.y, i0 = blockIdx.x*64;
  const float* xb = x + (size_t)b*FIN_*N_;
  for (int t = threadIdx.x; t < FIN_*64; t += 256){
    int c = t >> 6, ii = t & 63;
    xi[t] = xb[(size_t)c*N_ + i0 + ii];
  }
  __syncthreads();
  const int ty = threadIdx.x >> 4;      // 0..15: i group (4 i's)
  const int tx = threadIdx.x & 15;      // 0..15: j group (4 j's per step)
  const int ibase = ty*4;
  const f32x4 sqi = *(const f32x4*)&sq[b*N_ + i0 + ibase];
  float bd[4][10]; int bi[4][10];
  #pragma unroll
  for (int ii=0;ii<4;++ii)
    #pragma unroll
    for (int s=0;s<10;++s){ bd[ii][s] = 1e30f; bi[ii][s] = -1; }

  for (int j0 = 0; j0 < N_; j0 += 64){
    const int jb = j0 + tx*4;
    const float* xjp = xb + jb;
    f32x4 acc[4] = {};    // acc[ii][m]
    #pragma unroll 8
    for (int c = 0; c < FIN_; ++c){
      const f32x4 a  = *(const f32x4*)&xi[c*64 + ibase];
      const f32x4 bb = *(const f32x4*)&xjp[(size_t)c*N_];
      #pragma unroll
      for (int ii=0;ii<4;++ii){
        #pragma unroll
        for (int m=0;m<4;++m)
          acc[ii][m] = __fmaf_rn(a[ii], bb[m], acc[ii][m]);
      }
    }
    const f32x4 sqj = *(const f32x4*)&sq[b*N_ + jb];
    #pragma unroll
    for (int ii=0;ii<4;++ii){
      const int i = i0 + ibase + ii;
      #pragma unroll
      for (int m=0;m<4;++m){
        int j = jb + m;
        float d = __fadd_rn(__fadd_rn(__fmul_rn(-2.f, acc[ii][m]), sqi[ii]), sqj[m]);
        if (j == i) d = 1e30f;
        if (d < bd[ii][9]){
          bd[ii][9] = d; bi[ii][9] = j;
          #pragma unroll
          for (int s = 9; s > 0; --s){
            if (bd[ii][s] < bd[ii][s-1]){
              float td = bd[ii][s]; bd[ii][s] = bd[ii][s-1]; bd[ii][s-1] = td;
              int ti = bi[ii][s]; bi[ii][s] = bi[ii][s-1]; bi[ii][s-1] = ti;
            }
          }
        }
      }
    }
  }

  __syncthreads();   // xi dead; reuse smem for merge buffers
  float* dbuf = (float*)smem;                               // [(list*10+s)*64 + ilocal] (40 KB)
  unsigned short* ibuf = (unsigned short*)(smem + 40960);   // same index (20 KB)
  #pragma unroll
  for (int ii=0;ii<4;++ii)
    #pragma unroll
    for (int s=0;s<10;++s){
      dbuf[(tx*10+s)*64 + ibase+ii] = bd[ii][s];
      ibuf[(tx*10+s)*64 + ibase+ii] = (unsigned short)bi[ii][s];
    }
  __syncthreads();
  if (threadIdx.x < 64){
    const int rr = threadIdx.x;
    int p[16];
    #pragma unroll
    for (int qq=0;qq<16;++qq) p[qq]=0;
    int* op = idx + ((size_t)b*N_ + i0 + rr)*K_;
    for (int s = 0; s < K_; ++s){
      float dm = 1e38f; int im = 0x7fffffff; int qm = 0;
      #pragma unroll
      for (int qq = 0; qq < 16; ++qq){
        int pq = p[qq];
        float d  = (pq < 10) ? dbuf[(qq*10+pq)*64 + rr] : 1e38f;
        int   jd = (pq < 10) ? (int)ibuf[(qq*10+pq)*64 + rr] : 0x7fffffff;
        bool take = (d < dm) || (d == dm && jd < im);
        if (take){ dm = d; im = jd; qm = qq; }
      }
      #pragma unroll
      for (int qq = 0; qq < 16; ++qq) if (qm == qq) p[qq]++;
      op[s] = im;
    }
  }
}

// ---------------- prepZ: per point, base = Wf_self.x - Wf_diff.x, z = Wf_diff.x ----------------
// Strength reduction for fx_stats: y[px,kk] = base[px] + z[j] (the 128x16 diff-dot distributes).
__global__ __launch_bounds__(256) void k_prepZ(const float* __restrict__ xT, const float* __restrict__ Wf,
                                               float* __restrict__ zbuf){
  __shared__ float wfT[256*16];
  for (int t = threadIdx.x; t < 256*16; t += 256){ int c = t >> 4, o = t & 15; wfT[t] = Wf[o*256 + c]; }
  __syncthreads();
  const int id = blockIdx.x*256 + threadIdx.x;
  const float* xs = xT + (size_t)id*FIN_;
  float yc[16], z[16];
  #pragma unroll
  for (int o=0;o<16;++o){ yc[o]=0.f; z[o]=0.f; }
  for (int c=0;c<FIN_;c+=4){
    const f32x4 v4 = *(const f32x4*)&xs[c];
    #pragma unroll
    for (int e=0;e<4;++e){
      float v = v4[e];
      #pragma unroll
      for (int o=0;o<16;++o){
        yc[o] += wfT[(c+e)*16+o]*v;
        z[o]  += wfT[(128+c+e)*16+o]*v;
      }
    }
  }
  float* zb = zbuf + (size_t)id*32;
  #pragma unroll
  for (int o=0;o<16;++o){ zb[o] = yc[o] - z[o]; zb[16+o] = z[o]; }
}

// ---------------- conv_f / conv_x stats (zbuf-fed; spills y/vx to ytmp) ----------------
// y = base[px] + z[j]: per-(px,kk) work collapses to a 64B L2-resident gather + 16 adds.
__global__ __launch_bounds__(256) void k_fx_stats(const float* __restrict__ zbuf, const float* __restrict__ pc,
                                                  const int* __restrict__ idx, const float* __restrict__ Wx,
                                                  float* __restrict__ stats, float* __restrict__ ytmp){
  __shared__ float wxT[6*16];
  if (threadIdx.x < 96){ int cc = threadIdx.x >> 4, o = threadIdx.x & 15; wxT[cc*16+o] = Wx[o*6+cc]; }
  __syncthreads();
  const int id = blockIdx.x*256 + threadIdx.x;
  const int b = id >> 11, n = id & (N_-1);
  const float* pb = pc + (size_t)b*3*N_;
  float base[16];
  {
    const float* zb = zbuf + (size_t)id*32;
    #pragma unroll
    for (int o=0;o<16;++o) base[o] = zb[o];
  }
  float p0=pb[n], p1=pb[N_+n], p2=pb[2*N_+n];
  float sf[16], ssf[16], sx[16], ssx[16];
  #pragma unroll
  for (int o=0;o<16;++o){ sf[o]=0.f;ssf[o]=0.f;sx[o]=0.f;ssx[o]=0.f; }
  for (int kk=0;kk<K_;++kk){
    int j = idx[(size_t)id*K_ + kk];
    const float* zj = zbuf + ((size_t)(b*N_ + j))*32 + 16;
    float y[16];
    #pragma unroll
    for (int o=0;o<16;o+=4){
      const f32x4 zv = *(const f32x4*)&zj[o];
      y[o+0]=base[o+0]+zv.x; y[o+1]=base[o+1]+zv.y; y[o+2]=base[o+2]+zv.z; y[o+3]=base[o+3]+zv.w;
    }
    float q0=pb[j]-p0, q1=pb[N_+j]-p1, q2=pb[2*N_+j]-p2;
    float vx[16];
    #pragma unroll
    for (int o=0;o<16;++o){
      vx[o] = wxT[0*16+o]*p0 + wxT[1*16+o]*p1 + wxT[2*16+o]*p2
            + wxT[3*16+o]*q0 + wxT[4*16+o]*q1 + wxT[5*16+o]*q2;
    }
    #pragma unroll
    for (int o=0;o<16;++o){
      sf[o]+=y[o]; ssf[o]+=y[o]*y[o];
      sx[o]+=vx[o]; ssx[o]+=vx[o]*vx[o];
    }
    float* yt = ytmp + ((size_t)id*K_ + kk)*32;
    #pragma unroll
    for (int o=0;o<16;++o){ yt[o] = y[o]; yt[16+o] = vx[o]; }
  }
  #pragma unroll
  for (int o=0;o<16;++o){
    float v;
    v = wave_sum(sf[o]);  if ((threadIdx.x&63)==0) atomicAdd(&stats[SUM_F+o], v);
    v = wave_sum(ssf[o]); if ((threadIdx.x&63)==0) atomicAdd(&stats[SS_F+o], v);
    v = wave_sum(sx[o]);  if ((threadIdx.x&63)==0) atomicAdd(&stats[SUM_X+o], v);
    v = wave_sum(ssx[o]); if ((threadIdx.x&63)==0) atomicAdd(&stats[SS_X+o], v);
  }
}

// ---------------- finalize BN: scale/shift from sums ----------------
__global__ void k_finalize(float* stats, int sumoff, int ssoff, int nch, float cnt_inv,
                           const float* __restrict__ g, const float* __restrict__ bt,
                           int scoff, int shoff){
  int c = threadIdx.x;
  if (c < nch){
    float mean = stats[sumoff+c]*cnt_inv;
    float var  = stats[ssoff+c]*cnt_inv - mean*mean;
    float rstd = rsqrtf(var + EPS_);
    float sc = g[c]*rstd;
    stats[scoff+c] = sc;
    stats[shoff+c] = bt[c] - mean*sc;
  }
}

// ---------------- wprod apply: wp = lrelu(bn_f(y))*lrelu(bn_x(vx)) from ytmp ----------------
__global__ __launch_bounds__(256) void k_wapply(const float* __restrict__ ytmp, const float* __restrict__ stats,
                                                float* __restrict__ wprod){
  __shared__ float s4[64];   // scf[16] shf[16] scx[16] shx[16] (stats 2240..2304 contiguous)
  if (threadIdx.x < 64) s4[threadIdx.x] = stats[SCALE_F + threadIdx.x];
  __syncthreads();
  const int e = blockIdx.x*256 + threadIdx.x;   // < 327680
  const float* yt = ytmp + (size_t)e*32;
  float* wp = wprod + (size_t)e*16;
  #pragma unroll
  for (int o=0;o<16;++o){
    float a  = lrelu(yt[o]*s4[o] + s4[16+o]);
    float bb = lrelu(yt[16+o]*s4[32+o] + s4[48+o]);
    wp[o] = a*bb;
  }
}

// ---------------- a1 stats (conv 16->64 over wprod) ----------------
__global__ __launch_bounds__(256) void k_a1_stats(const float* __restrict__ wprod, const float* __restrict__ Wa1,
                                                  float* __restrict__ stats){
  __shared__ float wp[64*16];
  const int oc = threadIdx.x & 63, sub = threadIdx.x >> 6;
  float wa[16];
  #pragma unroll
  for (int j = 0; j < 16; ++j) wa[j] = Wa1[oc*16+j];
  float s = 0.f, ss = 0.f;
  for (int tile = blockIdx.x; tile < 5120; tile += gridDim.x){
    __syncthreads();
    for (int t = threadIdx.x; t < 1024; t += 256) wp[t] = wprod[(size_t)tile*1024 + t];
    __syncthreads();
    for (int p = sub*16; p < sub*16+16; ++p){
      float y = 0.f;
      #pragma unroll
      for (int j = 0; j < 16; ++j) y += wa[j]*wp[p*16+j];
      s += y; ss += y*y;
    }
  }
  atomicAdd(&stats[SUM_A1+oc], s);
  atomicAdd(&stats[SS_A1+oc], ss);
}

// ---------------- a2 Gram accumulate: S2 = Σ a1, G2 = Σ a1 a1^T over all (px,kk) ----------------
__global__ __launch_bounds__(256) void k_a2g(const float* __restrict__ wprod, const float* __restrict__ Wa1,
                                             const float* __restrict__ stats, float* __restrict__ aux){
  __shared__ float wp[64*16];
  __shared__ float a1t[64*64];
  __shared__ float wa1T[16*64];
  __shared__ float sc1[64], sh1[64];
  for (int t=threadIdx.x;t<1024;t+=256){ int j=t&63, jj=t>>6; wa1T[jj*64+j] = Wa1[j*16+jj]; }
  if (threadIdx.x < 64){ sc1[threadIdx.x]=stats[SCALE_A1+threadIdx.x]; sh1[threadIdx.x]=stats[SHIFT_A1+threadIdx.x]; }
  const int i  = threadIdx.x >> 2;   // 0..63: Gram row
  const int jq = threadIdx.x & 3;    // 0..3: 16-col quad
  f32x4 g0={0.f,0.f,0.f,0.f}, g1={0.f,0.f,0.f,0.f}, g2={0.f,0.f,0.f,0.f}, g3={0.f,0.f,0.f,0.f};
  float s = 0.f;
  for (int tile = blockIdx.x; tile < 5120; tile += gridDim.x){
    __syncthreads();
    for (int t=threadIdx.x;t<1024;t+=256) wp[t] = wprod[(size_t)tile*1024 + t];
    __syncthreads();
    for (int t=threadIdx.x;t<4096;t+=256){
      int p = t >> 6, j = t & 63;
      float yv=0.f;
      #pragma unroll
      for (int jj=0;jj<16;++jj) yv += wa1T[jj*64+j]*wp[p*16+jj];
      a1t[t] = lrelu(yv*sc1[j]+sh1[j]);
    }
    __syncthreads();
    #pragma unroll 4
    for (int p=0;p<64;++p){
      const float ai = a1t[p*64 + i];
      const f32x4* row = (const f32x4*)&a1t[p*64 + jq*16];
      g0 += ai*row[0]; g1 += ai*row[1]; g2 += ai*row[2]; g3 += ai*row[3];
      if (jq == 0) s += ai;
    }
  }
  float* G = aux + 64;
  const int base = i*64 + jq*16;
  #pragma unroll
  for (int r=0;r<4;++r){ atomicAdd(&G[base+r],    g0[r]); }
  #pragma unroll
  for (int r=0;r<4;++r){ atomicAdd(&G[base+4+r],  g1[r]); }
  #pragma unroll
  for (int r=0;r<4;++r){ atomicAdd(&G[base+8+r],  g2[r]); }
  #pragma unroll
  for (int r=0;r<4;++r){ atomicAdd(&G[base+12+r], g3[r]); }
  if (jq == 0) atomicAdd(&aux[i], s);
}

// ---------------- a2 finalize from Gram: SUM_A2 = w.S2, SS_A2 = w^T G2 w ----------------
__global__ void k_a2fin(const float* __restrict__ aux, const float* __restrict__ Wa2,
                        float* __restrict__ stats){
  __shared__ float G[4096];
  __shared__ float S[64];
  for (int t = threadIdx.x; t < 4096; t += 256) G[t] = aux[64 + t];
  if (threadIdx.x < 64) S[threadIdx.x] = aux[threadIdx.x];
  __syncthreads();
  const int oc = threadIdx.x;
  float w[64];
  #pragma unroll
  for (int j=0;j<64;++j) w[j] = Wa2[oc*64+j];
  float sum = 0.f;
  #pragma unroll
  for (int j=0;j<64;++j) sum += w[j]*S[j];
  float ss = 0.f;
  for (int i=0;i<64;++i){
    float gi = 0.f;
    #pragma unroll
    for (int j=0;j<64;++j) gi += w[j]*G[i*64+j];
    ss += w[i]*gi;
  }
  stats[SUM_A2+oc] = sum;
  stats[SS_A2+oc]  = ss;
}

// ---------------- prep Ai for conv_Wi t5-split GEMM ----------------
__global__ __launch_bounds__(256) void k_prepAi(const float* __restrict__ Wi, unsigned short* __restrict__ Ai){
  const int total = 512*896;
  for (int e = blockIdx.x*256 + threadIdx.x; e < total; e += gridDim.x*256){
    int o = e / 896, k = e - o*896;
    float v;
    if (k < 768){
      int u = k >> 7, c = k & 127;
      v = Wi[(size_t)o*1536 + (128+c)*6 + u];
    } else {
      const float* p = &Wi[(size_t)o*1536 + (size_t)(k-768)*6];
      v = p[0]+p[1]+p[2]+p[3]+p[4]+p[5];
    }
    Ai[e] = f2bf(v);
  }
}

// ---------------- prep A2 hi/lo for W2 refolded GEMM ----------------
__global__ __launch_bounds__(256) void k_prepA2(const float* __restrict__ W2,
                                                unsigned short* __restrict__ A2hi,
                                                unsigned short* __restrict__ A2lo){
  const int total = 256*KW2_;
  for (int e = blockIdx.x*256 + threadIdx.x; e < total; e += gridDim.x*256){
    int oc = e / KW2_, k = e - oc*KW2_;
    const float* wr = &W2[(size_t)oc*5120];
    float v;
    if (k < 2560){
      int o = k & 511, t5 = k >> 9;
      int cch = o >> 1, w = (o & 1)*5 + t5;
      v = wr[cch*20 + 10 + w];
    } else if (k < 3840){
      int kk = k - 2560; int w = kk >> 7, c = kk & 127;
      v = wr[(128+c)*20 + w];
    } else {
      int c = k - 3840;
      float s = 0.f;
      #pragma unroll
      for (int w = 0; w < 10; ++w) s += wr[c*20+w] - wr[(128+c)*20+w];
      v = s;
    }
    unsigned short hi = f2bf(v);
    float lo = v - bf2f(hi);
    A2hi[e] = hi;
    A2lo[e] = f2bf(lo);
  }
}

// ---------------- gather: Bd[pxl][slab*128+c] bf16, slabs 0..9 = diff(x_jw - x_self), 10 = self ----------------
__global__ __launch_bounds__(256) void k_gather(const float* __restrict__ xT, const int* __restrict__ idx,
                                                unsigned short* __restrict__ Bd, int pxbase){
  const int e = blockIdx.x*256 + threadIdx.x;   // < CHUNK_*16
  const int pxl = e >> 4, sub = e & 15;
  const int px = pxbase + pxl;
  const int c0 = sub*8;
  const float* xs = xT + (size_t)px*FIN_ + c0;
  const f32x4 s0 = *(const f32x4*)&xs[0];
  const f32x4 s1 = *(const f32x4*)&xs[4];
  unsigned short* bo = Bd + (size_t)pxl*1408;
  const size_t bb = (size_t)(px >> 11)*N_*FIN_;
  const int* ip = idx + (size_t)px*K_;
  #pragma unroll
  for (int w = 0; w < 10; ++w){
    int j = ip[w];
    const float* xj = xT + bb + (size_t)j*FIN_ + c0;
    const f32x4 a0 = *(const f32x4*)&xj[0];
    const f32x4 a1 = *(const f32x4*)&xj[4];
    unsigned short tw[8];
    tw[0]=f2bf(a0.x-s0.x); tw[1]=f2bf(a0.y-s0.y); tw[2]=f2bf(a0.z-s0.z); tw[3]=f2bf(a0.w-s0.w);
    tw[4]=f2bf(a1.x-s1.x); tw[5]=f2bf(a1.y-s1.y); tw[6]=f2bf(a1.z-s1.z); tw[7]=f2bf(a1.w-s1.w);
    *(s16x8*)&bo[w*128 + c0] = *(const s16x8*)tw;
  }
  unsigned short tw[8];
  tw[0]=f2bf(s0.x); tw[1]=f2bf(s0.y); tw[2]=f2bf(s0.z); tw[3]=f2bf(s0.w);
  tw[4]=f2bf(s1.x); tw[5]=f2bf(s1.y); tw[6]=f2bf(s1.z); tw[7]=f2bf(s1.w);
  *(s16x8*)&bo[1280 + c0] = *(const s16x8*)tw;
}

// ---------------- conv_Wi t5-split GEMM (bf16 MFMA), Bd-fed: per t5: C[512 x CHUNK] = Ai * B_t5 ----------------
__global__ __launch_bounds__(256) void k_gemmI(const unsigned short* __restrict__ Bd,
                                               const unsigned short* __restrict__ Ai,
                                               __hip_bfloat16* __restrict__ ybuf, float* __restrict__ stats,
                                               int pxbase){
  __shared__ __align__(16) unsigned short As[128*72];
  __shared__ __align__(16) unsigned short Bs[128*72];
  const int o0 = blockIdx.x * 128;     // 4 row tiles (o)
  const int c0 = blockIdx.y * 128;     // CHUNK_/128 col tiles (local px)
  const int t5 = blockIdx.z;           // 5
  const int rowA = threadIdx.x >> 1;
  const int kA   = (threadIdx.x & 1)*32;
  const unsigned short* arow = Ai + (size_t)(o0+rowA)*896 + kA;
  const int colJ = threadIdx.x >> 1;
  const int kB   = (threadIdx.x & 1)*32;
  const unsigned short* brow = Bd + (size_t)(c0 + colJ)*1408;
  const int wave = threadIdx.x >> 6, lane = threadIdx.x & 63;
  const int quad = lane >> 4, l16 = lane & 15;
  const int wm = wave & 1, wn = wave >> 1;

  f32x4 acc[4][4] = {};

  for (int k0 = 0; k0 < 896; k0 += 64){
    __syncthreads();
    {
      unsigned short* dst = &As[rowA*72 + kA];
      *(s16x8*)&dst[0]  = *(const s16x8*)&arow[k0+0];
      *(s16x8*)&dst[8]  = *(const s16x8*)&arow[k0+8];
      *(s16x8*)&dst[16] = *(const s16x8*)&arow[k0+16];
      *(s16x8*)&dst[24] = *(const s16x8*)&arow[k0+24];
    }
    {
      const int kk = k0 + kB;          // 32-aligned; band/self boundary (768) never splits a run
      const unsigned short* src = brow + ((kk < 768) ? ((t5 + (kk >> 7))*128 + (kk & 127))
                                                     : (1280 + (kk - 768)));
      unsigned short* dst = &Bs[colJ*72 + kB];
      *(s16x8*)&dst[0]  = *(const s16x8*)&src[0];
      *(s16x8*)&dst[8]  = *(const s16x8*)&src[8];
      *(s16x8*)&dst[16] = *(const s16x8*)&src[16];
      *(s16x8*)&dst[24] = *(const s16x8*)&src[24];
    }
    __syncthreads();
    #pragma unroll
    for (int ks = 0; ks < 2; ++ks){
      s16x8 af[4], bfr[4];
      #pragma unroll
      for (int mt = 0; mt < 4; ++mt)
        af[mt] = *(const s16x8*)&As[(wm*64 + mt*16 + l16)*72 + ks*32 + quad*8];
      #pragma unroll
      for (int nt = 0; nt < 4; ++nt)
        bfr[nt] = *(const s16x8*)&Bs[(wn*64 + nt*16 + l16)*72 + ks*32 + quad*8];
      #pragma unroll
      for (int mt = 0; mt < 4; ++mt)
        #pragma unroll
        for (int nt = 0; nt < 4; ++nt)
          acc[mt][nt] = __builtin_amdgcn_mfma_f32_16x16x32_bf16(af[mt], bfr[nt], acc[mt][nt], 0, 0, 0);
    }
  }

  __syncthreads();
  float* red = (float*)As;   // reuse (256 floats)
  red[threadIdx.x] = 0.f;
  __syncthreads();
  #pragma unroll
  for (int mt = 0; mt < 4; ++mt){
    const int rowLbase = wm*64 + mt*16 + quad*4;
    #pragma unroll
    for (int reg = 0; reg < 4; ++reg){
      float s = 0.f, ss = 0.f;
      #pragma unroll
      for (int nt = 0; nt < 4; ++nt){ float v = acc[mt][nt][reg]; s += v; ss += v*v; }
      atomicAdd(&red[(rowLbase+reg)*2+0], s);
      atomicAdd(&red[(rowLbase+reg)*2+1], ss);
    }
  }
  #pragma unroll
  for (int mt = 0; mt < 4; ++mt){
    #pragma unroll
    for (int nt = 0; nt < 4; ++nt){
      const int px = pxbase + c0 + wn*64 + nt*16 + l16;
      const int ob = wm*64 + mt*16 + quad*4;
      s16x4 w;
      #pragma unroll
      for (int reg = 0; reg < 4; ++reg) w[reg] = (short)f2bf(acc[mt][nt][reg]);
      *(s16x4*)&ybuf[(size_t)px*2560 + t5*512 + o0 + ob] = w;
    }
  }
  __syncthreads();
  if (threadIdx.x < 128){
    atomicAdd(&stats[SUM_I + o0 + threadIdx.x], red[threadIdx.x*2+0]);
    atomicAdd(&stats[SS_I + o0 + threadIdx.x], red[threadIdx.x*2+1]);
  }
}

// ---------------- w-chain + softmax + bn_i + interleave-multiply (in-place on ybuf, bf16) ----------------
// Persistent blocks: wa1T/sc/sh staged once, Wa2 row held in VGPRs (f32x4[16]); 16 px per block.
__global__ __launch_bounds__(256, 4) void k_wchain(const float* __restrict__ wprod, const float* __restrict__ Wa1,
                                                   const float* __restrict__ Wa2, const float* __restrict__ stats,
                                                   __hip_bfloat16* __restrict__ ybuf, int pxPerBlk){
  __shared__ float wp[160];
  __shared__ float a1l[640];
  __shared__ float wa1T[16*64];
  __shared__ float sc1[64], sh1[64];
  for (int t = threadIdx.x; t < 1024; t += 256){ int j = t & 63, jj = t >> 6; wa1T[jj*64+j] = Wa1[j*16+jj]; }
  if (threadIdx.x < 64){ sc1[threadIdx.x]=stats[SCALE_A1+threadIdx.x]; sh1[threadIdx.x]=stats[SHIFT_A1+threadIdx.x]; }
  const int c = threadIdx.x;
  f32x4 wa2v[16];
  #pragma unroll
  for (int j4=0;j4<16;++j4) wa2v[j4] = *(const f32x4*)&Wa2[c*64 + j4*4];
  const float sc2 = stats[SCALE_A2+c], sh2 = stats[SHIFT_A2+c];
  const float sci0 = stats[SCALE_I + 2*c], shi0 = stats[SHIFT_I + 2*c];
  const float sci1 = stats[SCALE_I + 2*c+1], shi1 = stats[SHIFT_I + 2*c+1];

  for (int pp = 0; pp < pxPerBlk; ++pp){
    const size_t px = (size_t)blockIdx.x*pxPerBlk + pp;
    __syncthreads();
    if (threadIdx.x < 160) wp[threadIdx.x] = wprod[px*160 + threadIdx.x];
    __syncthreads();
    for (int t = threadIdx.x; t < 640; t += 256){
      int kk = t >> 6, j = t & 63;
      float y=0.f;
      #pragma unroll
      for (int jj=0;jj<16;++jj) y += wa1T[jj*64+j]*wp[kk*16+jj];
      a1l[kk*64+j] = lrelu(y*sc1[j]+sh1[j]);
    }
    __syncthreads();
    float wt[10];
    #pragma unroll
    for (int kk=0;kk<10;++kk){
      f32x4 acc = {0.f,0.f,0.f,0.f};
      #pragma unroll
      for (int j4=0;j4<16;++j4){
        const f32x4 a = *(const f32x4*)&a1l[kk*64 + j4*4];
        acc += wa2v[j4]*a;
      }
      float y = (acc.x+acc.y)+(acc.z+acc.w);
      wt[kk] = lrelu(y*sc2+sh2);
    }
    float mx = wt[0];
    #pragma unroll
    for (int kk=1;kk<10;++kk) mx = fmaxf(mx, wt[kk]);
    float sum = 0.f;
    #pragma unroll
    for (int kk=0;kk<10;++kk){ wt[kk] = __expf(wt[kk]-mx); sum += wt[kk]; }
    float inv = 1.f/sum;
    __hip_bfloat16* yb = ybuf + px*2560;
    #pragma unroll
    for (int q = 0; q < 10; ++q){
      const int t5q = (q < 5) ? q : q-5;
      const int ii  = t5q*512 + 2*c + ((q < 5) ? 0 : 1);
      float v = __bfloat162float(yb[ii]);
      float sc = (q < 5) ? sci0 : sci1;
      float sh = (q < 5) ? shi0 : shi1;
      yb[ii] = __float2bfloat16(lrelu(v*sc+sh) * (wt[q]*inv));
    }
  }
}

// ---------------- W2 refolded GEMM (split-bf16 MFMA): outpre[256 x 32768]; fused o-stats ----------------
__global__ __launch_bounds__(256) void k_w2(const float* __restrict__ xT, const int* __restrict__ idx,
                                            const __hip_bfloat16* __restrict__ inte,
                                            const unsigned short* __restrict__ A2hi,
                                            const unsigned short* __restrict__ A2lo,
                                            float* __restrict__ outpre, float* __restrict__ stats){
  __shared__ __align__(16) unsigned short AsH[128*40];
  __shared__ __align__(16) unsigned short AsL[128*40];
  __shared__ __align__(16) unsigned short BsH[128*40];
  __shared__ __align__(16) unsigned short BsL[128*40];
  __shared__ int sIdx[128*10];
  const int r0 = blockIdx.x * 128;   // 2 row tiles (oc)
  const int c0 = blockIdx.y * 128;   // 256 col tiles (px)
  for (int t = threadIdx.x; t < 1280; t += 256) sIdx[t] = idx[(size_t)c0*10 + t];
  const int rowA  = threadIdx.x >> 1;
  const int halfA = threadIdx.x & 1;
  const unsigned short* ahrow = A2hi + (size_t)(r0+rowA)*KW2_ + halfA*16;
  const unsigned short* alrow = A2lo + (size_t)(r0+rowA)*KW2_ + halfA*16;
  const int colJ  = threadIdx.x >> 1;
  const int cHalf = (threadIdx.x & 1)*16;
  const int pxJ   = c0 + colJ;
  const size_t selfJ  = (size_t)pxJ*FIN_;
  const size_t bbaseJ = (size_t)(pxJ >> 11)*N_*FIN_;
  const __hip_bfloat16* ibJ = inte + (size_t)pxJ*2560;
  const int wave = threadIdx.x >> 6, lane = threadIdx.x & 63;
  const int quad = lane >> 4, l16 = lane & 15;
  const int wm = wave & 1, wn = wave >> 1;

  f32x4 acc[4][4] = {};

  for (int k0 = 0; k0 < KW2_; k0 += 32){
    __syncthreads();
    {
      *(s16x8*)&AsH[rowA*40 + halfA*16]     = *(const s16x8*)&ahrow[k0];
      *(s16x8*)&AsH[rowA*40 + halfA*16 + 8] = *(const s16x8*)&ahrow[k0+8];
      *(s16x8*)&AsL[rowA*40 + halfA*16]     = *(const s16x8*)&alrow[k0];
      *(s16x8*)&AsL[rowA*40 + halfA*16 + 8] = *(const s16x8*)&alrow[k0+8];
    }
    if (k0 < 2560){
      *(s16x8*)&BsH[colJ*40 + cHalf]     = *(const s16x8*)(ibJ + k0 + cHalf);
      *(s16x8*)&BsH[colJ*40 + cHalf + 8] = *(const s16x8*)(ibJ + k0 + cHalf + 8);
    } else {
      const float* src;
      if (k0 < 3840){
        const int w  = (k0 - 2560) >> 7;
        const int cb = ((k0 - 2560) & 127) + cHalf;
        const int j  = sIdx[colJ*10 + w];
        src = &xT[bbaseJ + (size_t)j*FIN_ + cb];
      } else {
        src = &xT[selfJ + (k0 - 3840) + cHalf];
      }
      unsigned short th[16], tl[16];
      #pragma unroll
      for (int q = 0; q < 4; ++q){
        const f32x4 v = *(const f32x4*)&src[q*4];
        #pragma unroll
        for (int e2 = 0; e2 < 4; ++e2){
          float f = v[e2];
          unsigned short h = f2bf(f);
          float r = f - bf2f(h);
          th[q*4+e2] = h;
          tl[q*4+e2] = f2bf(r);
        }
      }
      *(s16x8*)&BsH[colJ*40 + cHalf]     = *(const s16x8*)&th[0];
      *(s16x8*)&BsH[colJ*40 + cHalf + 8] = *(const s16x8*)&th[8];
      *(s16x8*)&BsL[colJ*40 + cHalf]     = *(const s16x8*)&tl[0];
      *(s16x8*)&BsL[colJ*40 + cHalf + 8] = *(const s16x8*)&tl[8];
    }
    __syncthreads();
    s16x8 ah[4], al[4], bh[4];
    #pragma unroll
    for (int mt = 0; mt < 4; ++mt){
      ah[mt] = *(const s16x8*)&AsH[(wm*64 + mt*16 + l16)*40 + quad*8];
      al[mt] = *(const s16x8*)&AsL[(wm*64 + mt*16 + l16)*40 + quad*8];
    }
    #pragma unroll
    for (int nt = 0; nt < 4; ++nt)
      bh[nt] = *(const s16x8*)&BsH[(wn*64 + nt*16 + l16)*40 + quad*8];
    #pragma unroll
    for (int mt = 0; mt < 4; ++mt)
      #pragma unroll
      for (int nt = 0; nt < 4; ++nt){
        acc[mt][nt] = __builtin_amdgcn_mfma_f32_16x16x32_bf16(ah[mt], bh[nt], acc[mt][nt], 0, 0, 0);
        acc[mt][nt] = __builtin_amdgcn_mfma_f32_16x16x32_bf16(al[mt], bh[nt], acc[mt][nt], 0, 0, 0);
      }
    if (k0 >= 2560){
      s16x8 bl[4];
      #pragma unroll
      for (int nt = 0; nt < 4; ++nt)
        bl[nt] = *(const s16x8*)&BsL[(wn*64 + nt*16 + l16)*40 + quad*8];
      #pragma unroll
      for (int mt = 0; mt < 4; ++mt)
        #pragma unroll
        for (int nt = 0; nt < 4; ++nt)
          acc[mt][nt] = __builtin_amdgcn_mfma_f32_16x16x32_bf16(ah[mt], bl[nt], acc[mt][nt], 0, 0, 0);
    }
  }

  __syncthreads();
  float* red = (float*)AsH;   // reuse (256 floats)
  red[threadIdx.x] = 0.f;
  __syncthreads();
  #pragma unroll
  for (int mt = 0; mt < 4; ++mt){
    const int rowLbase = wm*64 + mt*16 + quad*4;
    #pragma unroll
    for (int reg = 0; reg < 4; ++reg){
      float s = 0.f, ss = 0.f;
      #pragma unroll
      for (int nt = 0; nt < 4; ++nt){ float v = acc[mt][nt][reg]; s += v; ss += v*v; }
      atomicAdd(&red[(rowLbase+reg)*2+0], s);
      atomicAdd(&red[(rowLbase+reg)*2+1], ss);
    }
  }
  #pragma unroll
  for (int mt = 0; mt < 4; ++mt){
    #pragma unroll
    for (int nt = 0; nt < 4; ++nt){
      const int col = c0 + wn*64 + nt*16 + l16;
      const int rowb = r0 + wm*64 + mt*16 + quad*4;
      #pragma unroll
      for (int reg = 0; reg < 4; ++reg)
        outpre[(size_t)(rowb+reg)*32768 + col] = acc[mt][nt][reg];
    }
  }
  __syncthreads();
  if (threadIdx.x < 128){
    atomicAdd(&stats[SUM_O + r0 + threadIdx.x], red[threadIdx.x*2+0]);
    atomicAdd(&stats[SS_O + r0 + threadIdx.x], red[threadIdx.x*2+1]);
  }
}

// ---------------- final: bn2 + relu + reshape to [B,128,4096] ----------------
__global__ __launch_bounds__(256) void k_final(const float* __restrict__ outpre, const float* __restrict__ stats,
                                               float* __restrict__ out){
  const unsigned total = (unsigned)B_*128u*4096u;
  for (unsigned e = blockIdx.x*256u + threadIdx.x; e < total; e += gridDim.x*256u){
    unsigned b = e >> 19;
    unsigned rem = e & ((1u<<19)-1u);
    unsigned f = rem >> 12;
    unsigned m = rem & 4095u;
    unsigned half = m >> 11;
    unsigned n = m & 2047u;
    unsigned c = f*2u + half;
    float pre = outpre[(size_t)c*32768 + b*2048 + n];
    float v = pre*stats[SCALE_O+c] + stats[SHIFT_O+c];
    out[e] = fmaxf(v, 0.f);
  }
}

extern "C" void kernel_launch(void* const* d_in, const int* in_sizes, int n_in,
                              void* d_out, int out_size, void* d_ws, size_t ws_size,
                              hipStream_t stream) {
  (void)in_sizes; (void)n_in; (void)out_size;
  const float* x    = (const float*)d_in[0];
  const float* pc   = (const float*)d_in[1];
  const float* Wf   = (const float*)d_in[2];
  const float* gf   = (const float*)d_in[4];
  const float* btf  = (const float*)d_in[5];
  const float* Wx   = (const float*)d_in[6];
  const float* gx   = (const float*)d_in[8];
  const float* btx  = (const float*)d_in[9];
  const float* Wa1  = (const float*)d_in[10];
  const float* ga1  = (const float*)d_in[12];
  const float* bta1 = (const float*)d_in[13];
  const float* Wa2  = (const float*)d_in[14];
  const float* ga2  = (const float*)d_in[16];
  const float* bta2 = (const float*)d_in[17];
  const float* Wi   = (const float*)d_in[18];
  const float* gi   = (const float*)d_in[20];
  const float* bti  = (const float*)d_in[21];
  const float* W2   = (const float*)d_in[22];
  const float* g2   = (const float*)d_in[24];
  const float* bt2  = (const float*)d_in[25];
  float* out = (float*)d_out;

  char* ws = (char*)d_ws;
  float*  stats  = (float*)ws;                          //        0 ..    32768
  int*    idx    = (int*)  (ws + 32768);                //    32768 ..  1343488
  float*  sq     = (float*)(ws + 1343488);              //  1343488 ..  1605632 (uses first 131072)
  float*  aux    = (float*)(ws + 1474560);              //  S2[64]+G2[4096] in sq tail (dead after knn)
  float*  wprod  = (float*)(ws + 1605632);              //  1605632 .. 22577152
  // zbuf (fp32 [32768 x 32] = 4,194,304 B) overlaps wprod head: written by k_prepZ, consumed by
  // k_fx_stats; wprod written afterwards by k_wapply.
  float*  zbuf   = (float*)(ws + 1605632);
  float*  xT     = (float*)(ws + 22577152);             // 22577152 .. 39354368
  // A2hi/A2lo bf16 [256 x 3968] = 2,031,616 B each -> 39354368 .. 43417600
  unsigned short* A2hi = (unsigned short*)(ws + 39354368);
  unsigned short* A2lo = (unsigned short*)(ws + 41385984);
  float*  outpre = (float*)(ws + 44597248);             // 44597248 .. 78151680
  // Ai (bf16 [512x896] = 917,504 B) at 44597248..45514752; Bd chunk (bf16 [8192x1408] = 23,068,672 B)
  // at 45645824..68714496 — both inside outpre region, consumed before k_w2 writes outpre.
  unsigned short* Ai = (unsigned short*)(ws + 44597248);
  unsigned short* Bd = (unsigned short*)(ws + 45645824);
  __hip_bfloat16* ybuf = (__hip_bfloat16*)(ws + 78151680); // 78151680 .. 245923840
  // ytmp (fp32 [327680 x 32] = 41,943,040 B) overlaps ybuf: consumed by k_wapply before k_gemmI writes ybuf.
  float* ytmp = (float*)(ws + 78151680);
  if (ws_size < 245923840ULL) {
    fprintf(stderr, "kernel_launch: ws_size %zu < required 245923840\n", ws_size);
    return;
  }

  k_zero<<<1, 256, 0, stream>>>(stats, aux);
  k_xt<<<dim3(FIN_/32, N_/32, B_), 256, 0, stream>>>(x, xT);
  k_sq<<<(B_*N_)/256, 256, 0, stream>>>(x, sq);
  k_knn<<<dim3(N_/64, B_), 256, 0, stream>>>(x, sq, idx);
  k_prepZ<<<(B_*N_)/256, 256, 0, stream>>>(xT, Wf, zbuf);
  k_prepAi<<<1024, 256, 0, stream>>>(Wi, Ai);
  k_prepA2<<<1024, 256, 0, stream>>>(W2, A2hi, A2lo);

  k_fx_stats<<<(B_*N_)/256, 256, 0, stream>>>(zbuf, pc, idx, Wx, stats, ytmp);
  k_finalize<<<1, 512, 0, stream>>>(stats, SUM_F, SS_F, 16, 1.f/327680.f, gf, btf, SCALE_F, SHIFT_F);
  k_finalize<<<1, 512, 0, stream>>>(stats, SUM_X, SS_X, 16, 1.f/327680.f, gx, btx, SCALE_X, SHIFT_X);

  k_wapply<<<1280, 256, 0, stream>>>(ytmp, stats, wprod);
  k_a1_stats<<<512, 256, 0, stream>>>(wprod, Wa1, stats);
  k_finalize<<<1, 512, 0, stream>>>(stats, SUM_A1, SS_A1, 64, 1.f/327680.f, ga1, bta1, SCALE_A1, SHIFT_A1);

  k_a2g<<<512, 256, 0, stream>>>(wprod, Wa1, stats, aux);
  k_a2fin<<<1, 256, 0, stream>>>(aux, Wa2, stats);
  k_finalize<<<1, 512, 0, stream>>>(stats, SUM_A2, SS_A2, 256, 1.f/327680.f, ga2, bta2, SCALE_A2, SHIFT_A2);

  for (int ch = 0; ch < (B_*N_)/CHUNK_; ++ch){
    k_gather<<<(CHUNK_*16)/256, 256, 0, stream>>>(xT, idx, Bd, ch*CHUNK_);
    k_gemmI<<<dim3(4, CHUNK_/128, 5), 256, 0, stream>>>(Bd, Ai, ybuf, stats, ch*CHUNK_);
  }
  k_finalize<<<1, 512, 0, stream>>>(stats, SUM_I, SS_I, 512, 1.f/163840.f, gi, bti, SCALE_I, SHIFT_I);

  k_wchain<<<2048, 256, 0, stream>>>(wprod, Wa1, Wa2, stats, ybuf, (B_*N_)/2048);

  k_w2<<<dim3(2, 256), 256, 0, stream>>>(xT, idx, ybuf, A2hi, A2lo, outpre, stats);
  k_finalize<<<1, 512, 0, stream>>>(stats, SUM_O, SS_O, 256, 1.f/32768.f, g2, bt2, SCALE_O, SHIFT_O);

  k_final<<<4096, 256, 0, stream>>>(outpre, stats, out);
}